// Round 1
// baseline (1489.323 us; speedup 1.0000x reference)
//
#include <hip/hip_runtime.h>
#include <math.h>

#define N_NODES 100000
#define N_EDGES 1600000
#define DIM 64
#define N_GRAPHS 256
#define BN_EPS 1e-5f

// ---------------- degree ----------------
__global__ void deg_init(float* deg) {
    int i = blockIdx.x * blockDim.x + threadIdx.x;
    if (i < N_NODES) deg[i] = 1.0f;   // self loop
}

__global__ void deg_count(const int* __restrict__ dst, float* deg) {
    int e = blockIdx.x * blockDim.x + threadIdx.x;
    if (e < N_EDGES) unsafeAtomicAdd(&deg[dst[e]], 1.0f);
}

__global__ void deg_finalize(float* deg) {
    int i = blockIdx.x * blockDim.x + threadIdx.x;
    if (i < N_NODES) deg[i] = rsqrtf(deg[i]);   // becomes dinv
}

// ---------------- GEMM: t = h @ W  (N x 64  @  64 x 64) ----------------
__global__ __launch_bounds__(256) void gemm64(const float* __restrict__ h,
                                              const float* __restrict__ W,
                                              float* __restrict__ t) {
    __shared__ float Ws[64 * 64];
    int tid = threadIdx.x;
    #pragma unroll
    for (int i = 0; i < 16; ++i) Ws[i * 256 + tid] = W[i * 256 + tid];
    __syncthreads();

    int d = tid & 63;
    int g = tid >> 6;                       // 0..3
    int row0 = blockIdx.x * 16 + g * 4;     // 16 rows per block
    #pragma unroll
    for (int r = 0; r < 4; ++r) {
        int row = row0 + r;
        if (row >= N_NODES) return;
        const float4* hv = reinterpret_cast<const float4*>(h + (size_t)row * 64);
        float acc = 0.f;
        #pragma unroll
        for (int k4 = 0; k4 < 16; ++k4) {
            float4 hk = hv[k4];
            acc += hk.x * Ws[(k4 * 4 + 0) * 64 + d];
            acc += hk.y * Ws[(k4 * 4 + 1) * 64 + d];
            acc += hk.z * Ws[(k4 * 4 + 2) * 64 + d];
            acc += hk.w * Ws[(k4 * 4 + 3) * 64 + d];
        }
        t[(size_t)row * 64 + d] = acc;
    }
}

// ---------------- out = bias + dinv^2 * t  (self-loop + init) ----------------
__global__ void self_init(const float* __restrict__ t, const float* __restrict__ dinv,
                          const float* __restrict__ bias, float* __restrict__ out) {
    int idx = blockIdx.x * blockDim.x + threadIdx.x;
    if (idx >= N_NODES * DIM) return;
    int v = idx >> 6;
    int d = idx & 63;
    float di = dinv[v];
    out[idx] = bias[d] + di * di * t[idx];
}

// ---------------- edge scatter: out[dst] += dinv[src]*dinv[dst] * t[src] ----------------
__global__ __launch_bounds__(256) void edge_scatter(const int* __restrict__ src,
                                                    const int* __restrict__ dst,
                                                    const float* __restrict__ dinv,
                                                    const float* __restrict__ t,
                                                    float* __restrict__ out) {
    int e = blockIdx.x * 4 + (threadIdx.x >> 6);
    if (e >= N_EDGES) return;
    int d = threadIdx.x & 63;
    int s = src[e];
    int v = dst[e];
    float nrm = dinv[s] * dinv[v];
    unsafeAtomicAdd(&out[(size_t)v * 64 + d], nrm * t[(size_t)s * 64 + d]);
}

// ---------------- BatchNorm stats: stats[0:64]=sum, stats[64:128]=sumsq ----------------
__global__ __launch_bounds__(256) void bn_stats(const float* __restrict__ h,
                                                float* __restrict__ stats) {
    int d = threadIdx.x & 63;
    int g = threadIdx.x >> 6;
    float s = 0.f, sq = 0.f;
    for (int row = blockIdx.x * 4 + g; row < N_NODES; row += gridDim.x * 4) {
        float v = h[(size_t)row * 64 + d];
        s += v;
        sq += v * v;
    }
    __shared__ float sh[8][64];
    sh[g][d] = s;
    sh[4 + g][d] = sq;
    __syncthreads();
    if (threadIdx.x < 64) {
        int dd = threadIdx.x;
        float S  = sh[0][dd] + sh[1][dd] + sh[2][dd] + sh[3][dd];
        float SQ = sh[4][dd] + sh[5][dd] + sh[6][dd] + sh[7][dd];
        unsafeAtomicAdd(&stats[dd], S);
        unsafeAtomicAdd(&stats[64 + dd], SQ);
    }
}

// ---------------- BatchNorm apply (+ optional ReLU), in place ----------------
__global__ void bn_apply(float* h, const float* __restrict__ stats,
                         const float* __restrict__ gamma, const float* __restrict__ beta,
                         int relu) {
    int idx = blockIdx.x * blockDim.x + threadIdx.x;
    if (idx >= N_NODES * DIM) return;
    int d = idx & 63;
    const float inv_n = 1.0f / (float)N_NODES;
    float mean = stats[d] * inv_n;
    float var = stats[64 + d] * inv_n - mean * mean;
    var = fmaxf(var, 0.f);
    float v = (h[idx] - mean) * rsqrtf(var + BN_EPS) * gamma[d] + beta[d];
    if (relu) v = fmaxf(v, 0.f);
    h[idx] = v;
}

// ---------------- per-graph mean+max pool ----------------
__global__ __launch_bounds__(256) void pool(const float* __restrict__ h,
                                            const int* __restrict__ batch,
                                            float* __restrict__ out) {
    int gph = blockIdx.x;
    __shared__ int bounds[2];
    if (threadIdx.x < 2) {
        int target = gph + (int)threadIdx.x;
        int lo = 0, hi = N_NODES;
        while (lo < hi) {
            int mid = (lo + hi) >> 1;
            if (batch[mid] < target) lo = mid + 1; else hi = mid;
        }
        bounds[threadIdx.x] = lo;
    }
    __syncthreads();
    int lo = bounds[0], hi = bounds[1];
    int d = threadIdx.x & 63;
    int g = threadIdx.x >> 6;
    float s = 0.f, m = -3.402823466e38f;
    for (int row = lo + g; row < hi; row += 4) {
        float v = h[(size_t)row * 64 + d];
        s += v;
        m = fmaxf(m, v);
    }
    __shared__ float sh[8][64];
    sh[g][d] = s;
    sh[4 + g][d] = m;
    __syncthreads();
    if (threadIdx.x < 64) {
        int dd = threadIdx.x;
        float S = sh[0][dd] + sh[1][dd] + sh[2][dd] + sh[3][dd];
        float M = fmaxf(fmaxf(sh[4][dd], sh[5][dd]), fmaxf(sh[6][dd], sh[7][dd]));
        int cnt = hi - lo;
        float mean = S / fmaxf((float)cnt, 1.0f);
        float mx = (cnt > 0) ? M : 0.0f;
        out[gph * 64 + dd] = mean + mx;
    }
}

extern "C" void kernel_launch(void* const* d_in, const int* in_sizes, int n_in,
                              void* d_out, int out_size, void* d_ws, size_t ws_size,
                              hipStream_t stream) {
    const float* x     = (const float*)d_in[0];
    const int*   eidx  = (const int*)d_in[1];
    const int*   batch = (const int*)d_in[2];
    const float* W[3]  = {(const float*)d_in[3], (const float*)d_in[7],  (const float*)d_in[11]};
    const float* b[3]  = {(const float*)d_in[4], (const float*)d_in[8],  (const float*)d_in[12]};
    const float* gm[3] = {(const float*)d_in[5], (const float*)d_in[9],  (const float*)d_in[13]};
    const float* be[3] = {(const float*)d_in[6], (const float*)d_in[10], (const float*)d_in[14]};

    float* bufA  = (float*)d_ws;                 // N*64
    float* bufB  = bufA + (size_t)N_NODES * 64;  // N*64
    float* dinv  = bufB + (size_t)N_NODES * 64;  // N
    float* stats = dinv + N_NODES;               // 128

    const int* srcp = eidx;
    const int* dstp = eidx + N_EDGES;

    deg_init<<<(N_NODES + 255) / 256, 256, 0, stream>>>(dinv);
    deg_count<<<(N_EDGES + 255) / 256, 256, 0, stream>>>(dstp, dinv);
    deg_finalize<<<(N_NODES + 255) / 256, 256, 0, stream>>>(dinv);

    const float* hin = x;
    for (int layer = 0; layer < 3; ++layer) {
        gemm64<<<(N_NODES + 15) / 16, 256, 0, stream>>>(hin, W[layer], bufB);
        self_init<<<(N_NODES * DIM + 255) / 256, 256, 0, stream>>>(bufB, dinv, b[layer], bufA);
        edge_scatter<<<N_EDGES / 4, 256, 0, stream>>>(srcp, dstp, dinv, bufB, bufA);
        hipMemsetAsync(stats, 0, 128 * sizeof(float), stream);
        bn_stats<<<1024, 256, 0, stream>>>(bufA, stats);
        bn_apply<<<(N_NODES * DIM + 255) / 256, 256, 0, stream>>>(bufA, stats, gm[layer], be[layer],
                                                                  layer < 2 ? 1 : 0);
        hin = bufA;
    }
    pool<<<N_GRAPHS, 256, 0, stream>>>(bufA, batch, (float*)d_out);
}

// Round 2
// 1138.236 us; speedup vs baseline: 1.3084x; 1.3084x over previous
//
#include <hip/hip_runtime.h>
#include <math.h>

#define N_NODES 100000
#define N_EDGES 1600000
#define DIM 64
#define N_GRAPHS 256
#define BN_EPS 1e-5f
#define SCAN_THREADS 1024
#define SCAN_CHUNK 98   // ceil(100000/1024)

// ---------------- CSR build ----------------
__global__ void hist_kernel(const int* __restrict__ dst, int* __restrict__ cnt) {
    int e = blockIdx.x * blockDim.x + threadIdx.x;
    if (e < N_EDGES) atomicAdd(&cnt[dst[e]], 1);
}

__global__ __launch_bounds__(1024) void scan_kernel(const int* __restrict__ cnt,
                                                    int* __restrict__ row_off,
                                                    float* __restrict__ dinv) {
    __shared__ int part[SCAN_THREADS];
    int tid = threadIdx.x;
    int base = tid * SCAN_CHUNK;
    int mysum = 0;
    #pragma unroll 4
    for (int i = 0; i < SCAN_CHUNK; ++i) {
        int idx = base + i;
        if (idx < N_NODES) mysum += cnt[idx];
    }
    part[tid] = mysum;
    __syncthreads();
    for (int off = 1; off < SCAN_THREADS; off <<= 1) {
        int v = (tid >= off) ? part[tid - off] : 0;
        __syncthreads();
        part[tid] += v;
        __syncthreads();
    }
    int running = part[tid] - mysum;   // exclusive prefix for my chunk
    for (int i = 0; i < SCAN_CHUNK; ++i) {
        int idx = base + i;
        if (idx < N_NODES) {
            int c = cnt[idx];
            row_off[idx] = running;
            running += c;
            dinv[idx] = rsqrtf((float)(c + 1));   // self loop included
        }
    }
    if (tid == 0) row_off[N_NODES] = N_EDGES;
}

__global__ void fill_kernel(const int* __restrict__ src, const int* __restrict__ dst,
                            const int* __restrict__ row_off, int* __restrict__ cursor,
                            int* __restrict__ csr_src) {
    int e = blockIdx.x * blockDim.x + threadIdx.x;
    if (e >= N_EDGES) return;
    int d = dst[e];
    int pos = row_off[d] + atomicAdd(&cursor[d], 1);
    csr_src[pos] = src[e];
}

// ---------------- layer-0 GEMM: t = dinv[row] * (x @ W) ----------------
__global__ __launch_bounds__(256) void gemm_l0(const float* __restrict__ h,
                                               const float* __restrict__ W,
                                               const float* __restrict__ dinv,
                                               float* __restrict__ t) {
    __shared__ float Ws[64 * 64];
    int tid = threadIdx.x;
    #pragma unroll
    for (int i = 0; i < 16; ++i) Ws[i * 256 + tid] = W[i * 256 + tid];
    __syncthreads();
    int d = tid & 63, g = tid >> 6;
    int row0 = blockIdx.x * 16 + g * 4;
    #pragma unroll
    for (int r = 0; r < 4; ++r) {
        int row = row0 + r;
        if (row >= N_NODES) return;
        const float4* hv = reinterpret_cast<const float4*>(h + (size_t)row * 64);
        float acc = 0.f;
        #pragma unroll
        for (int k4 = 0; k4 < 16; ++k4) {
            float4 hk = hv[k4];
            acc = fmaf(hk.x, Ws[(k4 * 4 + 0) * 64 + d], acc);
            acc = fmaf(hk.y, Ws[(k4 * 4 + 1) * 64 + d], acc);
            acc = fmaf(hk.z, Ws[(k4 * 4 + 2) * 64 + d], acc);
            acc = fmaf(hk.w, Ws[(k4 * 4 + 3) * 64 + d], acc);
        }
        t[(size_t)row * 64 + d] = acc * dinv[row];
    }
}

// ------- fused BN(stats of prev agg) + ReLU + GEMM: t = dinv[row]*(bnrelu(h) @ W) -------
__global__ __launch_bounds__(256) void bn_gemm(const float* __restrict__ h,
                                               const float* __restrict__ stats,
                                               const float* __restrict__ gamma,
                                               const float* __restrict__ beta,
                                               const float* __restrict__ W,
                                               const float* __restrict__ dinv,
                                               float* __restrict__ t) {
    __shared__ float Ws[64 * 64];
    __shared__ float scale[64], shift[64];
    int tid = threadIdx.x;
    #pragma unroll
    for (int i = 0; i < 16; ++i) Ws[i * 256 + tid] = W[i * 256 + tid];
    if (tid < 64) {
        const float inv_n = 1.0f / (float)N_NODES;
        float mean = stats[tid] * inv_n;
        float var = fmaxf(stats[64 + tid] * inv_n - mean * mean, 0.f);
        float rs = rsqrtf(var + BN_EPS) * gamma[tid];
        scale[tid] = rs;
        shift[tid] = beta[tid] - mean * rs;
    }
    __syncthreads();
    int d = tid & 63, g = tid >> 6;
    int row0 = blockIdx.x * 16 + g * 4;
    #pragma unroll
    for (int r = 0; r < 4; ++r) {
        int row = row0 + r;
        if (row >= N_NODES) return;
        const float4* hv = reinterpret_cast<const float4*>(h + (size_t)row * 64);
        float acc = 0.f;
        #pragma unroll
        for (int k4 = 0; k4 < 16; ++k4) {
            float4 hk = hv[k4];
            int k = k4 * 4;
            float a0 = fmaxf(fmaf(hk.x, scale[k + 0], shift[k + 0]), 0.f);
            float a1 = fmaxf(fmaf(hk.y, scale[k + 1], shift[k + 1]), 0.f);
            float a2 = fmaxf(fmaf(hk.z, scale[k + 2], shift[k + 2]), 0.f);
            float a3 = fmaxf(fmaf(hk.w, scale[k + 3], shift[k + 3]), 0.f);
            acc = fmaf(a0, Ws[(k + 0) * 64 + d], acc);
            acc = fmaf(a1, Ws[(k + 1) * 64 + d], acc);
            acc = fmaf(a2, Ws[(k + 2) * 64 + d], acc);
            acc = fmaf(a3, Ws[(k + 3) * 64 + d], acc);
        }
        t[(size_t)row * 64 + d] = acc * dinv[row];
    }
}

// ------- CSR segment gather + self loop + bias, fused BN-stats partials -------
__global__ __launch_bounds__(256) void gather_agg(const int* __restrict__ csr_src,
                                                  const int* __restrict__ row_off,
                                                  const float* __restrict__ dinv,
                                                  const float* __restrict__ t,
                                                  const float* __restrict__ bias,
                                                  float* __restrict__ out,
                                                  float* __restrict__ stats) {
    int d = threadIdx.x & 63, g = threadIdx.x >> 6;
    float s = 0.f, sq = 0.f;
    for (int v = blockIdx.x * 4 + g; v < N_NODES; v += gridDim.x * 4) {
        int beg = row_off[v], end = row_off[v + 1];
        float acc = t[(size_t)v * 64 + d];          // self loop (dinv folded in t)
        int e = beg;
        int sidx = (e < end) ? csr_src[e] : 0;
        while (e < end) {
            int cur = sidx;
            ++e;
            if (e < end) sidx = csr_src[e];         // prefetch next src index
            acc += t[(size_t)cur * 64 + d];
        }
        float val = fmaf(dinv[v], acc, bias[d]);
        out[(size_t)v * 64 + d] = val;
        s += val;
        sq += val * val;
    }
    __shared__ float sh[8][64];
    sh[g][d] = s;
    sh[4 + g][d] = sq;
    __syncthreads();
    if (threadIdx.x < 64) {
        int dd = threadIdx.x;
        unsafeAtomicAdd(&stats[dd],      sh[0][dd] + sh[1][dd] + sh[2][dd] + sh[3][dd]);
        unsafeAtomicAdd(&stats[64 + dd], sh[4][dd] + sh[5][dd] + sh[6][dd] + sh[7][dd]);
    }
}

// ---------------- per-graph mean+max pool with inline final BN ----------------
__global__ __launch_bounds__(256) void pool_bn(const float* __restrict__ h,
                                               const int* __restrict__ batch,
                                               const float* __restrict__ stats,
                                               const float* __restrict__ gamma,
                                               const float* __restrict__ beta,
                                               float* __restrict__ out) {
    __shared__ float scale[64], shift[64];
    __shared__ int bounds[2];
    int tid = threadIdx.x;
    if (tid < 64) {
        const float inv_n = 1.0f / (float)N_NODES;
        float mean = stats[tid] * inv_n;
        float var = fmaxf(stats[64 + tid] * inv_n - mean * mean, 0.f);
        float rs = rsqrtf(var + BN_EPS) * gamma[tid];
        scale[tid] = rs;
        shift[tid] = beta[tid] - mean * rs;
    }
    if (tid < 2) {
        int target = blockIdx.x + tid;
        int lo = 0, hi = N_NODES;
        while (lo < hi) {
            int mid = (lo + hi) >> 1;
            if (batch[mid] < target) lo = mid + 1; else hi = mid;
        }
        bounds[tid] = lo;
    }
    __syncthreads();
    int lo = bounds[0], hi = bounds[1];
    int d = tid & 63, g = tid >> 6;
    float s = 0.f, m = -3.402823466e38f;
    for (int row = lo + g; row < hi; row += 4) {
        float v = fmaf(h[(size_t)row * 64 + d], scale[d], shift[d]);
        s += v;
        m = fmaxf(m, v);
    }
    __shared__ float sh[8][64];
    sh[g][d] = s;
    sh[4 + g][d] = m;
    __syncthreads();
    if (tid < 64) {
        float S = sh[0][tid] + sh[1][tid] + sh[2][tid] + sh[3][tid];
        float M = fmaxf(fmaxf(sh[4][tid], sh[5][tid]), fmaxf(sh[6][tid], sh[7][tid]));
        int cnt = hi - lo;
        float mean = S / fmaxf((float)cnt, 1.0f);
        float mx = (cnt > 0) ? M : 0.0f;
        out[blockIdx.x * 64 + tid] = mean + mx;
    }
}

extern "C" void kernel_launch(void* const* d_in, const int* in_sizes, int n_in,
                              void* d_out, int out_size, void* d_ws, size_t ws_size,
                              hipStream_t stream) {
    const float* x     = (const float*)d_in[0];
    const int*   eidx  = (const int*)d_in[1];
    const int*   batch = (const int*)d_in[2];
    const float* W[3]  = {(const float*)d_in[3], (const float*)d_in[7],  (const float*)d_in[11]};
    const float* b[3]  = {(const float*)d_in[4], (const float*)d_in[8],  (const float*)d_in[12]};
    const float* gm[3] = {(const float*)d_in[5], (const float*)d_in[9],  (const float*)d_in[13]};
    const float* be[3] = {(const float*)d_in[6], (const float*)d_in[10], (const float*)d_in[14]};

    float* t       = (float*)d_ws;                   // N*64
    float* agg     = t + (size_t)N_NODES * 64;       // N*64
    float* dinv    = agg + (size_t)N_NODES * 64;     // N
    float* stats   = dinv + N_NODES;                 // 128
    int*   cnt     = (int*)(stats + 128);            // N
    int*   row_off = cnt + N_NODES;                  // N+1
    int*   cursor  = row_off + N_NODES + 1;          // N
    int*   csr_src = cursor + N_NODES;               // E

    const int* srcp = eidx;
    const int* dstp = eidx + N_EDGES;

    // CSR build (by destination) + dinv
    hipMemsetAsync(cnt, 0, N_NODES * sizeof(int), stream);
    hipMemsetAsync(cursor, 0, N_NODES * sizeof(int), stream);
    hist_kernel<<<(N_EDGES + 255) / 256, 256, 0, stream>>>(dstp, cnt);
    scan_kernel<<<1, SCAN_THREADS, 0, stream>>>(cnt, row_off, dinv);
    fill_kernel<<<(N_EDGES + 255) / 256, 256, 0, stream>>>(srcp, dstp, row_off, cursor, csr_src);

    const int gemm_grid = (N_NODES + 15) / 16;

    // layer 1
    gemm_l0<<<gemm_grid, 256, 0, stream>>>(x, W[0], dinv, t);
    hipMemsetAsync(stats, 0, 128 * sizeof(float), stream);
    gather_agg<<<1024, 256, 0, stream>>>(csr_src, row_off, dinv, t, b[0], agg, stats);

    // layer 2
    bn_gemm<<<gemm_grid, 256, 0, stream>>>(agg, stats, gm[0], be[0], W[1], dinv, t);
    hipMemsetAsync(stats, 0, 128 * sizeof(float), stream);
    gather_agg<<<1024, 256, 0, stream>>>(csr_src, row_off, dinv, t, b[1], agg, stats);

    // layer 3
    bn_gemm<<<gemm_grid, 256, 0, stream>>>(agg, stats, gm[1], be[1], W[2], dinv, t);
    hipMemsetAsync(stats, 0, 128 * sizeof(float), stream);
    gather_agg<<<1024, 256, 0, stream>>>(csr_src, row_off, dinv, t, b[2], agg, stats);

    // pool with inline BN3
    pool_bn<<<N_GRAPHS, 256, 0, stream>>>(agg, batch, stats, gm[2], be[2], (float*)d_out);
}

// Round 3
// 685.339 us; speedup vs baseline: 2.1731x; 1.6608x over previous
//
#include <hip/hip_runtime.h>
#include <math.h>

#define N_NODES 100000
#define N_EDGES 1600000
#define DIM 64
#define N_GRAPHS 256
#define BN_EPS 1e-5f
#define SCAN_BLOCK 1024
#define N_SCAN_BLOCKS ((N_NODES + SCAN_BLOCK - 1) / SCAN_BLOCK)   // 98

// ---------------- CSR build ----------------
__global__ void hist_kernel(const int* __restrict__ dst, int* __restrict__ cnt) {
    int e = blockIdx.x * blockDim.x + threadIdx.x;
    if (e < N_EDGES) atomicAdd(&cnt[dst[e]], 1);
}

// phase 1: per-block sums (256 thr x 4 elem)
__global__ __launch_bounds__(256) void scan_phase1(const int* __restrict__ cnt,
                                                   int* __restrict__ blocksums) {
    __shared__ int sh[256];
    int tid = threadIdx.x;
    int base = blockIdx.x * SCAN_BLOCK + tid * 4;
    int s = 0;
    if (base + 3 < N_NODES) {
        int4 c = *reinterpret_cast<const int4*>(cnt + base);
        s = c.x + c.y + c.z + c.w;
    } else {
        for (int i = 0; i < 4; ++i) if (base + i < N_NODES) s += cnt[base + i];
    }
    sh[tid] = s;
    __syncthreads();
    for (int off = 128; off > 0; off >>= 1) {
        if (tid < off) sh[tid] += sh[tid + off];
        __syncthreads();
    }
    if (tid == 0) blocksums[blockIdx.x] = sh[0];
}

// phase 2: exclusive scan of the 98 block sums (single small block)
__global__ __launch_bounds__(128) void scan_phase2(int* __restrict__ blocksums) {
    __shared__ int sh[128];
    int tid = threadIdx.x;
    int v = (tid < N_SCAN_BLOCKS) ? blocksums[tid] : 0;
    sh[tid] = v;
    __syncthreads();
    for (int off = 1; off < 128; off <<= 1) {
        int u = (tid >= off) ? sh[tid - off] : 0;
        __syncthreads();
        sh[tid] += u;
        __syncthreads();
    }
    if (tid < N_SCAN_BLOCKS) blocksums[tid] = sh[tid] - v;   // exclusive
}

// phase 3: intra-block scan + write row_off and dinv
__global__ __launch_bounds__(256) void scan_phase3(const int* __restrict__ cnt,
                                                   const int* __restrict__ blocksums,
                                                   int* __restrict__ row_off,
                                                   float* __restrict__ dinv) {
    __shared__ int sh[256];
    int tid = threadIdx.x;
    int base = blockIdx.x * SCAN_BLOCK + tid * 4;
    int c0 = 0, c1 = 0, c2 = 0, c3 = 0;
    if (base + 3 < N_NODES) {
        int4 cc = *reinterpret_cast<const int4*>(cnt + base);
        c0 = cc.x; c1 = cc.y; c2 = cc.z; c3 = cc.w;
    } else {
        if (base + 0 < N_NODES) c0 = cnt[base + 0];
        if (base + 1 < N_NODES) c1 = cnt[base + 1];
        if (base + 2 < N_NODES) c2 = cnt[base + 2];
        if (base + 3 < N_NODES) c3 = cnt[base + 3];
    }
    int mysum = c0 + c1 + c2 + c3;
    sh[tid] = mysum;
    __syncthreads();
    for (int off = 1; off < 256; off <<= 1) {
        int u = (tid >= off) ? sh[tid - off] : 0;
        __syncthreads();
        sh[tid] += u;
        __syncthreads();
    }
    int prefix = blocksums[blockIdx.x] + sh[tid] - mysum;
    int c[4] = {c0, c1, c2, c3};
    for (int i = 0; i < 4; ++i) {
        int idx = base + i;
        if (idx < N_NODES) {
            row_off[idx] = prefix;
            prefix += c[i];
            dinv[idx] = rsqrtf((float)(c[i] + 1));   // self loop included
        }
    }
    if (blockIdx.x == 0 && tid == 0) row_off[N_NODES] = N_EDGES;
}

__global__ void fill_kernel(const int* __restrict__ src, const int* __restrict__ dst,
                            const int* __restrict__ row_off, int* __restrict__ cursor,
                            int* __restrict__ csr_src) {
    int e = blockIdx.x * blockDim.x + threadIdx.x;
    if (e >= N_EDGES) return;
    int d = dst[e];
    int pos = row_off[d] + atomicAdd(&cursor[d], 1);
    csr_src[pos] = src[e];
}

// ---------------- layer-0 GEMM: t = dinv[row] * (x @ W) ----------------
__global__ __launch_bounds__(256) void gemm_l0(const float* __restrict__ h,
                                               const float* __restrict__ W,
                                               const float* __restrict__ dinv,
                                               float* __restrict__ t) {
    __shared__ float Ws[64 * 64];
    int tid = threadIdx.x;
    #pragma unroll
    for (int i = 0; i < 16; ++i) Ws[i * 256 + tid] = W[i * 256 + tid];
    __syncthreads();
    int d = tid & 63, g = tid >> 6;
    int row0 = blockIdx.x * 16 + g * 4;
    #pragma unroll
    for (int r = 0; r < 4; ++r) {
        int row = row0 + r;
        if (row >= N_NODES) return;
        const float4* hv = reinterpret_cast<const float4*>(h + (size_t)row * 64);
        float acc = 0.f;
        #pragma unroll
        for (int k4 = 0; k4 < 16; ++k4) {
            float4 hk = hv[k4];
            acc = fmaf(hk.x, Ws[(k4 * 4 + 0) * 64 + d], acc);
            acc = fmaf(hk.y, Ws[(k4 * 4 + 1) * 64 + d], acc);
            acc = fmaf(hk.z, Ws[(k4 * 4 + 2) * 64 + d], acc);
            acc = fmaf(hk.w, Ws[(k4 * 4 + 3) * 64 + d], acc);
        }
        t[(size_t)row * 64 + d] = acc * dinv[row];
    }
}

// ------- fused BN + ReLU + GEMM: t = dinv[row]*(bnrelu(h) @ W) -------
__global__ __launch_bounds__(256) void bn_gemm(const float* __restrict__ h,
                                               const float* __restrict__ stats,
                                               const float* __restrict__ gamma,
                                               const float* __restrict__ beta,
                                               const float* __restrict__ W,
                                               const float* __restrict__ dinv,
                                               float* __restrict__ t) {
    __shared__ float Ws[64 * 64];
    __shared__ float scale[64], shift[64];
    int tid = threadIdx.x;
    #pragma unroll
    for (int i = 0; i < 16; ++i) Ws[i * 256 + tid] = W[i * 256 + tid];
    if (tid < 64) {
        const float inv_n = 1.0f / (float)N_NODES;
        float mean = stats[tid] * inv_n;
        float var = fmaxf(stats[64 + tid] * inv_n - mean * mean, 0.f);
        float rs = rsqrtf(var + BN_EPS) * gamma[tid];
        scale[tid] = rs;
        shift[tid] = beta[tid] - mean * rs;
    }
    __syncthreads();
    int d = tid & 63, g = tid >> 6;
    int row0 = blockIdx.x * 16 + g * 4;
    #pragma unroll
    for (int r = 0; r < 4; ++r) {
        int row = row0 + r;
        if (row >= N_NODES) return;
        const float4* hv = reinterpret_cast<const float4*>(h + (size_t)row * 64);
        float acc = 0.f;
        #pragma unroll
        for (int k4 = 0; k4 < 16; ++k4) {
            float4 hk = hv[k4];
            int k = k4 * 4;
            float a0 = fmaxf(fmaf(hk.x, scale[k + 0], shift[k + 0]), 0.f);
            float a1 = fmaxf(fmaf(hk.y, scale[k + 1], shift[k + 1]), 0.f);
            float a2 = fmaxf(fmaf(hk.z, scale[k + 2], shift[k + 2]), 0.f);
            float a3 = fmaxf(fmaf(hk.w, scale[k + 3], shift[k + 3]), 0.f);
            acc = fmaf(a0, Ws[(k + 0) * 64 + d], acc);
            acc = fmaf(a1, Ws[(k + 1) * 64 + d], acc);
            acc = fmaf(a2, Ws[(k + 2) * 64 + d], acc);
            acc = fmaf(a3, Ws[(k + 3) * 64 + d], acc);
        }
        t[(size_t)row * 64 + d] = acc * dinv[row];
    }
}

// ------- CSR segment gather, quarter-per-edge float4 scheme -------
// wave = 1 node; 4x16-lane quarters each pull one edge's row as float4, x2 unroll.
__global__ __launch_bounds__(256) void gather_agg(const int* __restrict__ csr_src,
                                                  const int* __restrict__ row_off,
                                                  const float* __restrict__ dinv,
                                                  const float* __restrict__ t,
                                                  const float* __restrict__ bias,
                                                  float* __restrict__ out,
                                                  float* __restrict__ stats) {
    int tid = threadIdx.x;
    int wave = tid >> 6;
    int lane = tid & 63;
    int q    = lane >> 4;        // quarter 0..3 → edge offset
    int ql   = lane & 15;        // columns ql*4 .. ql*4+3

    float4 s4  = {0.f, 0.f, 0.f, 0.f};
    float4 sq4 = {0.f, 0.f, 0.f, 0.f};

    for (int v = blockIdx.x * 4 + wave; v < N_NODES; v += gridDim.x * 4) {
        int beg = row_off[v], end = row_off[v + 1];
        float4 acc  = {0.f, 0.f, 0.f, 0.f};
        float4 acc2 = {0.f, 0.f, 0.f, 0.f};
        int e = beg + q;
        for (; e + 4 < end; e += 8) {
            int s0 = csr_src[e];
            int s1 = csr_src[e + 4];
            float4 v0 = *reinterpret_cast<const float4*>(t + (size_t)s0 * 64 + ql * 4);
            float4 v1 = *reinterpret_cast<const float4*>(t + (size_t)s1 * 64 + ql * 4);
            acc.x  += v0.x; acc.y  += v0.y; acc.z  += v0.z; acc.w  += v0.w;
            acc2.x += v1.x; acc2.y += v1.y; acc2.z += v1.z; acc2.w += v1.w;
        }
        if (e < end) {
            int s0 = csr_src[e];
            float4 v0 = *reinterpret_cast<const float4*>(t + (size_t)s0 * 64 + ql * 4);
            acc.x += v0.x; acc.y += v0.y; acc.z += v0.z; acc.w += v0.w;
        }
        acc.x += acc2.x; acc.y += acc2.y; acc.z += acc2.z; acc.w += acc2.w;

        // combine quarters: lanes l, l^16, l^32, l^48 hold partials of same columns
        acc.x += __shfl_xor(acc.x, 16, 64); acc.x += __shfl_xor(acc.x, 32, 64);
        acc.y += __shfl_xor(acc.y, 16, 64); acc.y += __shfl_xor(acc.y, 32, 64);
        acc.z += __shfl_xor(acc.z, 16, 64); acc.z += __shfl_xor(acc.z, 32, 64);
        acc.w += __shfl_xor(acc.w, 16, 64); acc.w += __shfl_xor(acc.w, 32, 64);

        if (q == 0) {
            float di = dinv[v];
            float4 tv = *reinterpret_cast<const float4*>(t + (size_t)v * 64 + ql * 4);
            float4 bi = *reinterpret_cast<const float4*>(bias + ql * 4);
            float4 val;
            val.x = fmaf(di, acc.x + tv.x, bi.x);
            val.y = fmaf(di, acc.y + tv.y, bi.y);
            val.z = fmaf(di, acc.z + tv.z, bi.z);
            val.w = fmaf(di, acc.w + tv.w, bi.w);
            *reinterpret_cast<float4*>(out + (size_t)v * 64 + ql * 4) = val;
            s4.x += val.x; s4.y += val.y; s4.z += val.z; s4.w += val.w;
            sq4.x += val.x * val.x; sq4.y += val.y * val.y;
            sq4.z += val.z * val.z; sq4.w += val.w * val.w;
        }
    }

    __shared__ float shs[4][64];
    __shared__ float shq[4][64];
    if (q == 0) {
        *reinterpret_cast<float4*>(&shs[wave][ql * 4]) = s4;
        *reinterpret_cast<float4*>(&shq[wave][ql * 4]) = sq4;
    }
    __syncthreads();
    if (tid < 64) {
        float S = shs[0][tid] + shs[1][tid] + shs[2][tid] + shs[3][tid];
        float Q = shq[0][tid] + shq[1][tid] + shq[2][tid] + shq[3][tid];
        unsafeAtomicAdd(&stats[tid], S);
        unsafeAtomicAdd(&stats[64 + tid], Q);
    }
}

// ---------------- per-graph mean+max pool with inline final BN ----------------
__global__ __launch_bounds__(256) void pool_bn(const float* __restrict__ h,
                                               const int* __restrict__ batch,
                                               const float* __restrict__ stats,
                                               const float* __restrict__ gamma,
                                               const float* __restrict__ beta,
                                               float* __restrict__ out) {
    __shared__ float scale[64], shift[64];
    __shared__ int bounds[2];
    int tid = threadIdx.x;
    if (tid < 64) {
        const float inv_n = 1.0f / (float)N_NODES;
        float mean = stats[tid] * inv_n;
        float var = fmaxf(stats[64 + tid] * inv_n - mean * mean, 0.f);
        float rs = rsqrtf(var + BN_EPS) * gamma[tid];
        scale[tid] = rs;
        shift[tid] = beta[tid] - mean * rs;
    }
    if (tid < 2) {
        int target = blockIdx.x + tid;
        int lo = 0, hi = N_NODES;
        while (lo < hi) {
            int mid = (lo + hi) >> 1;
            if (batch[mid] < target) lo = mid + 1; else hi = mid;
        }
        bounds[tid] = lo;
    }
    __syncthreads();
    int lo = bounds[0], hi = bounds[1];
    int d = tid & 63, g = tid >> 6;
    float s = 0.f, m = -3.402823466e38f;
    for (int row = lo + g; row < hi; row += 4) {
        float v = fmaf(h[(size_t)row * 64 + d], scale[d], shift[d]);
        s += v;
        m = fmaxf(m, v);
    }
    __shared__ float sh[8][64];
    sh[g][d] = s;
    sh[4 + g][d] = m;
    __syncthreads();
    if (tid < 64) {
        float S = sh[0][tid] + sh[1][tid] + sh[2][tid] + sh[3][tid];
        float M = fmaxf(fmaxf(sh[4][tid], sh[5][tid]), fmaxf(sh[6][tid], sh[7][tid]));
        int cnt = hi - lo;
        float mean = S / fmaxf((float)cnt, 1.0f);
        float mx = (cnt > 0) ? M : 0.0f;
        out[blockIdx.x * 64 + tid] = mean + mx;
    }
}

extern "C" void kernel_launch(void* const* d_in, const int* in_sizes, int n_in,
                              void* d_out, int out_size, void* d_ws, size_t ws_size,
                              hipStream_t stream) {
    const float* x     = (const float*)d_in[0];
    const int*   eidx  = (const int*)d_in[1];
    const int*   batch = (const int*)d_in[2];
    const float* W[3]  = {(const float*)d_in[3], (const float*)d_in[7],  (const float*)d_in[11]};
    const float* b[3]  = {(const float*)d_in[4], (const float*)d_in[8],  (const float*)d_in[12]};
    const float* gm[3] = {(const float*)d_in[5], (const float*)d_in[9],  (const float*)d_in[13]};
    const float* be[3] = {(const float*)d_in[6], (const float*)d_in[10], (const float*)d_in[14]};

    float* t        = (float*)d_ws;                   // N*64
    float* agg      = t + (size_t)N_NODES * 64;       // N*64
    float* dinv     = agg + (size_t)N_NODES * 64;     // N
    float* stats    = dinv + N_NODES;                 // 128
    int*   cnt      = (int*)(stats + 128);            // N
    int*   row_off  = cnt + N_NODES;                  // N+1
    int*   cursor   = row_off + N_NODES + 1;          // N
    int*   blocksum = cursor + N_NODES;               // 98
    int*   csr_src  = blocksum + 128;                 // E

    const int* srcp = eidx;
    const int* dstp = eidx + N_EDGES;

    // CSR build (by destination) + dinv
    hipMemsetAsync(cnt, 0, N_NODES * sizeof(int), stream);
    hipMemsetAsync(cursor, 0, N_NODES * sizeof(int), stream);
    hist_kernel<<<(N_EDGES + 255) / 256, 256, 0, stream>>>(dstp, cnt);
    scan_phase1<<<N_SCAN_BLOCKS, 256, 0, stream>>>(cnt, blocksum);
    scan_phase2<<<1, 128, 0, stream>>>(blocksum);
    scan_phase3<<<N_SCAN_BLOCKS, 256, 0, stream>>>(cnt, blocksum, row_off, dinv);
    fill_kernel<<<(N_EDGES + 255) / 256, 256, 0, stream>>>(srcp, dstp, row_off, cursor, csr_src);

    const int gemm_grid = (N_NODES + 15) / 16;

    // layer 1
    gemm_l0<<<gemm_grid, 256, 0, stream>>>(x, W[0], dinv, t);
    hipMemsetAsync(stats, 0, 128 * sizeof(float), stream);
    gather_agg<<<2048, 256, 0, stream>>>(csr_src, row_off, dinv, t, b[0], agg, stats);

    // layer 2
    bn_gemm<<<gemm_grid, 256, 0, stream>>>(agg, stats, gm[0], be[0], W[1], dinv, t);
    hipMemsetAsync(stats, 0, 128 * sizeof(float), stream);
    gather_agg<<<2048, 256, 0, stream>>>(csr_src, row_off, dinv, t, b[1], agg, stats);

    // layer 3
    bn_gemm<<<gemm_grid, 256, 0, stream>>>(agg, stats, gm[1], be[1], W[2], dinv, t);
    hipMemsetAsync(stats, 0, 128 * sizeof(float), stream);
    gather_agg<<<2048, 256, 0, stream>>>(csr_src, row_off, dinv, t, b[2], agg, stats);

    // pool with inline BN3
    pool_bn<<<N_GRAPHS, 256, 0, stream>>>(agg, batch, stats, gm[2], be[2], (float*)d_out);
}

// Round 4
// 614.152 us; speedup vs baseline: 2.4250x; 1.1159x over previous
//
#include <hip/hip_runtime.h>
#include <hip/hip_bf16.h>
#include <math.h>

#define N_NODES 100000
#define N_EDGES 1600000
#define DIM 64
#define N_GRAPHS 256
#define BN_EPS 1e-5f
#define SCAN_BLOCK 1024
#define N_SCAN_BLOCKS ((N_NODES + SCAN_BLOCK - 1) / SCAN_BLOCK)   // 98
#define N_XCD 8
#define BUCKET ((N_NODES + N_XCD - 1) / N_XCD)                    // 12500
#define FILL_CHUNKS 128
#define FILL_ESIZE ((N_EDGES + FILL_CHUNKS - 1) / FILL_CHUNKS)    // 12500

__device__ inline unsigned short f2bf(float f) {
    __hip_bfloat16 h = __float2bfloat16(f);   // RNE
    return *reinterpret_cast<unsigned short*>(&h);
}

// ---------------- CSR build ----------------
__global__ void hist_kernel(const int* __restrict__ dst, int* __restrict__ cnt) {
    int e = blockIdx.x * blockDim.x + threadIdx.x;
    if (e < N_EDGES) atomicAdd(&cnt[dst[e]], 1);
}

__global__ __launch_bounds__(256) void scan_phase1(const int* __restrict__ cnt,
                                                   int* __restrict__ blocksums) {
    __shared__ int sh[256];
    int tid = threadIdx.x;
    int base = blockIdx.x * SCAN_BLOCK + tid * 4;
    int s = 0;
    if (base + 3 < N_NODES) {
        int4 c = *reinterpret_cast<const int4*>(cnt + base);
        s = c.x + c.y + c.z + c.w;
    } else {
        for (int i = 0; i < 4; ++i) if (base + i < N_NODES) s += cnt[base + i];
    }
    sh[tid] = s;
    __syncthreads();
    for (int off = 128; off > 0; off >>= 1) {
        if (tid < off) sh[tid] += sh[tid + off];
        __syncthreads();
    }
    if (tid == 0) blocksums[blockIdx.x] = sh[0];
}

__global__ __launch_bounds__(128) void scan_phase2(int* __restrict__ blocksums) {
    __shared__ int sh[128];
    int tid = threadIdx.x;
    int v = (tid < N_SCAN_BLOCKS) ? blocksums[tid] : 0;
    sh[tid] = v;
    __syncthreads();
    for (int off = 1; off < 128; off <<= 1) {
        int u = (tid >= off) ? sh[tid - off] : 0;
        __syncthreads();
        sh[tid] += u;
        __syncthreads();
    }
    if (tid < N_SCAN_BLOCKS) blocksums[tid] = sh[tid] - v;   // exclusive
}

__global__ __launch_bounds__(256) void scan_phase3(const int* __restrict__ cnt,
                                                   const int* __restrict__ blocksums,
                                                   int* __restrict__ row_off,
                                                   float* __restrict__ dinv) {
    __shared__ int sh[256];
    int tid = threadIdx.x;
    int base = blockIdx.x * SCAN_BLOCK + tid * 4;
    int c0 = 0, c1 = 0, c2 = 0, c3 = 0;
    if (base + 3 < N_NODES) {
        int4 cc = *reinterpret_cast<const int4*>(cnt + base);
        c0 = cc.x; c1 = cc.y; c2 = cc.z; c3 = cc.w;
    } else {
        if (base + 0 < N_NODES) c0 = cnt[base + 0];
        if (base + 1 < N_NODES) c1 = cnt[base + 1];
        if (base + 2 < N_NODES) c2 = cnt[base + 2];
        if (base + 3 < N_NODES) c3 = cnt[base + 3];
    }
    int mysum = c0 + c1 + c2 + c3;
    sh[tid] = mysum;
    __syncthreads();
    for (int off = 1; off < 256; off <<= 1) {
        int u = (tid >= off) ? sh[tid - off] : 0;
        __syncthreads();
        sh[tid] += u;
        __syncthreads();
    }
    int prefix = blocksums[blockIdx.x] + sh[tid] - mysum;
    int c[4] = {c0, c1, c2, c3};
    for (int i = 0; i < 4; ++i) {
        int idx = base + i;
        if (idx < N_NODES) {
            row_off[idx] = prefix;
            prefix += c[i];
            dinv[idx] = rsqrtf((float)(c[i] + 1));   // self loop included
        }
    }
    if (blockIdx.x == 0 && tid == 0) row_off[N_NODES] = N_EDGES;
}

// XCD-bucketed fill: block handles (chunk = bid>>3) x (dst-range = bid&7).
// blockIdx%8 round-robins onto XCDs, so each XCD's csr_src slice (~800 KB)
// stays resident in its own L2 -> cache lines fill before writeback.
__global__ __launch_bounds__(256) void fill_bucketed(const int* __restrict__ src,
                                                     const int* __restrict__ dst,
                                                     const int* __restrict__ row_off,
                                                     int* __restrict__ cursor,
                                                     int* __restrict__ csr_src) {
    int chunk = blockIdx.x >> 3;
    int lo = (blockIdx.x & (N_XCD - 1)) * BUCKET;
    int e0 = chunk * FILL_ESIZE;
    int e1 = min(e0 + FILL_ESIZE, N_EDGES);
    for (int e = e0 + threadIdx.x; e < e1; e += 256) {
        int d = dst[e];
        if ((unsigned)(d - lo) < (unsigned)BUCKET) {
            int pos = row_off[d] + atomicAdd(&cursor[d], 1);
            csr_src[pos] = src[e];
        }
    }
}

// ---------------- layer-0 GEMM: t = bf16(dinv[row] * (x @ W)) ----------------
__global__ __launch_bounds__(256) void gemm_l0(const float* __restrict__ h,
                                               const float* __restrict__ W,
                                               const float* __restrict__ dinv,
                                               unsigned short* __restrict__ tb) {
    __shared__ float Ws[64 * 64];
    int tid = threadIdx.x;
    #pragma unroll
    for (int i = 0; i < 16; ++i) Ws[i * 256 + tid] = W[i * 256 + tid];
    __syncthreads();
    int d = tid & 63, g = tid >> 6;
    int row0 = blockIdx.x * 16 + g * 4;
    #pragma unroll
    for (int r = 0; r < 4; ++r) {
        int row = row0 + r;
        if (row >= N_NODES) return;
        const float4* hv = reinterpret_cast<const float4*>(h + (size_t)row * 64);
        float acc = 0.f;
        #pragma unroll
        for (int k4 = 0; k4 < 16; ++k4) {
            float4 hk = hv[k4];
            acc = fmaf(hk.x, Ws[(k4 * 4 + 0) * 64 + d], acc);
            acc = fmaf(hk.y, Ws[(k4 * 4 + 1) * 64 + d], acc);
            acc = fmaf(hk.z, Ws[(k4 * 4 + 2) * 64 + d], acc);
            acc = fmaf(hk.w, Ws[(k4 * 4 + 3) * 64 + d], acc);
        }
        tb[(size_t)row * 64 + d] = f2bf(acc * dinv[row]);
    }
}

// ------- fused BN + ReLU + GEMM: t = bf16(dinv[row]*(bnrelu(h) @ W)) -------
__global__ __launch_bounds__(256) void bn_gemm(const float* __restrict__ h,
                                               const float* __restrict__ stats,
                                               const float* __restrict__ gamma,
                                               const float* __restrict__ beta,
                                               const float* __restrict__ W,
                                               const float* __restrict__ dinv,
                                               unsigned short* __restrict__ tb) {
    __shared__ float Ws[64 * 64];
    __shared__ float scale[64], shift[64];
    int tid = threadIdx.x;
    #pragma unroll
    for (int i = 0; i < 16; ++i) Ws[i * 256 + tid] = W[i * 256 + tid];
    if (tid < 64) {
        const float inv_n = 1.0f / (float)N_NODES;
        float mean = stats[tid] * inv_n;
        float var = fmaxf(stats[64 + tid] * inv_n - mean * mean, 0.f);
        float rs = rsqrtf(var + BN_EPS) * gamma[tid];
        scale[tid] = rs;
        shift[tid] = beta[tid] - mean * rs;
    }
    __syncthreads();
    int d = tid & 63, g = tid >> 6;
    int row0 = blockIdx.x * 16 + g * 4;
    #pragma unroll
    for (int r = 0; r < 4; ++r) {
        int row = row0 + r;
        if (row >= N_NODES) return;
        const float4* hv = reinterpret_cast<const float4*>(h + (size_t)row * 64);
        float acc = 0.f;
        #pragma unroll
        for (int k4 = 0; k4 < 16; ++k4) {
            float4 hk = hv[k4];
            int k = k4 * 4;
            float a0 = fmaxf(fmaf(hk.x, scale[k + 0], shift[k + 0]), 0.f);
            float a1 = fmaxf(fmaf(hk.y, scale[k + 1], shift[k + 1]), 0.f);
            float a2 = fmaxf(fmaf(hk.z, scale[k + 2], shift[k + 2]), 0.f);
            float a3 = fmaxf(fmaf(hk.w, scale[k + 3], shift[k + 3]), 0.f);
            acc = fmaf(a0, Ws[(k + 0) * 64 + d], acc);
            acc = fmaf(a1, Ws[(k + 1) * 64 + d], acc);
            acc = fmaf(a2, Ws[(k + 2) * 64 + d], acc);
            acc = fmaf(a3, Ws[(k + 3) * 64 + d], acc);
        }
        tb[(size_t)row * 64 + d] = f2bf(acc * dinv[row]);
    }
}

// ------- CSR segment gather over bf16 t; quarter-per-edge uint2 scheme -------
__global__ __launch_bounds__(256) void gather_agg(const int* __restrict__ csr_src,
                                                  const int* __restrict__ row_off,
                                                  const float* __restrict__ dinv,
                                                  const unsigned short* __restrict__ tb,
                                                  const float* __restrict__ bias,
                                                  float* __restrict__ out,
                                                  float* __restrict__ stats) {
    int tid = threadIdx.x;
    int wave = tid >> 6;
    int lane = tid & 63;
    int q    = lane >> 4;        // quarter 0..3 -> edge offset
    int ql   = lane & 15;        // columns ql*4 .. ql*4+3

    float4 s4  = {0.f, 0.f, 0.f, 0.f};
    float4 sq4 = {0.f, 0.f, 0.f, 0.f};

    for (int v = blockIdx.x * 4 + wave; v < N_NODES; v += gridDim.x * 4) {
        int beg = row_off[v], end = row_off[v + 1];
        float4 acc  = {0.f, 0.f, 0.f, 0.f};
        float4 acc2 = {0.f, 0.f, 0.f, 0.f};
        int e = beg + q;
        for (; e + 4 < end; e += 8) {
            int s0 = csr_src[e];
            int s1 = csr_src[e + 4];
            uint2 u0 = *reinterpret_cast<const uint2*>(tb + (size_t)s0 * 64 + ql * 4);
            uint2 u1 = *reinterpret_cast<const uint2*>(tb + (size_t)s1 * 64 + ql * 4);
            acc.x  += __uint_as_float(u0.x << 16);
            acc.y  += __uint_as_float(u0.x & 0xffff0000u);
            acc.z  += __uint_as_float(u0.y << 16);
            acc.w  += __uint_as_float(u0.y & 0xffff0000u);
            acc2.x += __uint_as_float(u1.x << 16);
            acc2.y += __uint_as_float(u1.x & 0xffff0000u);
            acc2.z += __uint_as_float(u1.y << 16);
            acc2.w += __uint_as_float(u1.y & 0xffff0000u);
        }
        if (e < end) {
            int s0 = csr_src[e];
            uint2 u0 = *reinterpret_cast<const uint2*>(tb + (size_t)s0 * 64 + ql * 4);
            acc.x += __uint_as_float(u0.x << 16);
            acc.y += __uint_as_float(u0.x & 0xffff0000u);
            acc.z += __uint_as_float(u0.y << 16);
            acc.w += __uint_as_float(u0.y & 0xffff0000u);
        }
        acc.x += acc2.x; acc.y += acc2.y; acc.z += acc2.z; acc.w += acc2.w;

        acc.x += __shfl_xor(acc.x, 16, 64); acc.x += __shfl_xor(acc.x, 32, 64);
        acc.y += __shfl_xor(acc.y, 16, 64); acc.y += __shfl_xor(acc.y, 32, 64);
        acc.z += __shfl_xor(acc.z, 16, 64); acc.z += __shfl_xor(acc.z, 32, 64);
        acc.w += __shfl_xor(acc.w, 16, 64); acc.w += __shfl_xor(acc.w, 32, 64);

        if (q == 0) {
            float di = dinv[v];
            uint2 uv = *reinterpret_cast<const uint2*>(tb + (size_t)v * 64 + ql * 4);
            float4 bi = *reinterpret_cast<const float4*>(bias + ql * 4);
            float4 val;
            val.x = fmaf(di, acc.x + __uint_as_float(uv.x << 16),        bi.x);
            val.y = fmaf(di, acc.y + __uint_as_float(uv.x & 0xffff0000u), bi.y);
            val.z = fmaf(di, acc.z + __uint_as_float(uv.y << 16),        bi.z);
            val.w = fmaf(di, acc.w + __uint_as_float(uv.y & 0xffff0000u), bi.w);
            *reinterpret_cast<float4*>(out + (size_t)v * 64 + ql * 4) = val;
            s4.x += val.x; s4.y += val.y; s4.z += val.z; s4.w += val.w;
            sq4.x += val.x * val.x; sq4.y += val.y * val.y;
            sq4.z += val.z * val.z; sq4.w += val.w * val.w;
        }
    }

    __shared__ float shs[4][64];
    __shared__ float shq[4][64];
    if (q == 0) {
        *reinterpret_cast<float4*>(&shs[wave][ql * 4]) = s4;
        *reinterpret_cast<float4*>(&shq[wave][ql * 4]) = sq4;
    }
    __syncthreads();
    if (tid < 64) {
        float S = shs[0][tid] + shs[1][tid] + shs[2][tid] + shs[3][tid];
        float Q = shq[0][tid] + shq[1][tid] + shq[2][tid] + shq[3][tid];
        unsafeAtomicAdd(&stats[tid], S);
        unsafeAtomicAdd(&stats[64 + tid], Q);
    }
}

// ---------------- per-graph mean+max pool with inline final BN ----------------
__global__ __launch_bounds__(256) void pool_bn(const float* __restrict__ h,
                                               const int* __restrict__ batch,
                                               const float* __restrict__ stats,
                                               const float* __restrict__ gamma,
                                               const float* __restrict__ beta,
                                               float* __restrict__ out) {
    __shared__ float scale[64], shift[64];
    __shared__ int bounds[2];
    int tid = threadIdx.x;
    if (tid < 64) {
        const float inv_n = 1.0f / (float)N_NODES;
        float mean = stats[tid] * inv_n;
        float var = fmaxf(stats[64 + tid] * inv_n - mean * mean, 0.f);
        float rs = rsqrtf(var + BN_EPS) * gamma[tid];
        scale[tid] = rs;
        shift[tid] = beta[tid] - mean * rs;
    }
    if (tid < 2) {
        int target = blockIdx.x + tid;
        int lo = 0, hi = N_NODES;
        while (lo < hi) {
            int mid = (lo + hi) >> 1;
            if (batch[mid] < target) lo = mid + 1; else hi = mid;
        }
        bounds[tid] = lo;
    }
    __syncthreads();
    int lo = bounds[0], hi = bounds[1];
    int d = tid & 63, g = tid >> 6;
    float s = 0.f, m = -3.402823466e38f;
    for (int row = lo + g; row < hi; row += 4) {
        float v = fmaf(h[(size_t)row * 64 + d], scale[d], shift[d]);
        s += v;
        m = fmaxf(m, v);
    }
    __shared__ float sh[8][64];
    sh[g][d] = s;
    sh[4 + g][d] = m;
    __syncthreads();
    if (tid < 64) {
        float S = sh[0][tid] + sh[1][tid] + sh[2][tid] + sh[3][tid];
        float M = fmaxf(fmaxf(sh[4][tid], sh[5][tid]), fmaxf(sh[6][tid], sh[7][tid]));
        int cnt = hi - lo;
        float mean = S / fmaxf((float)cnt, 1.0f);
        float mx = (cnt > 0) ? M : 0.0f;
        out[blockIdx.x * 64 + tid] = mean + mx;
    }
}

extern "C" void kernel_launch(void* const* d_in, const int* in_sizes, int n_in,
                              void* d_out, int out_size, void* d_ws, size_t ws_size,
                              hipStream_t stream) {
    const float* x     = (const float*)d_in[0];
    const int*   eidx  = (const int*)d_in[1];
    const int*   batch = (const int*)d_in[2];
    const float* W[3]  = {(const float*)d_in[3], (const float*)d_in[7],  (const float*)d_in[11]};
    const float* b[3]  = {(const float*)d_in[4], (const float*)d_in[8],  (const float*)d_in[12]};
    const float* gm[3] = {(const float*)d_in[5], (const float*)d_in[9],  (const float*)d_in[13]};
    const float* be[3] = {(const float*)d_in[6], (const float*)d_in[10], (const float*)d_in[14]};

    float*          agg      = (float*)d_ws;                       // N*64 f32
    unsigned short* tb       = (unsigned short*)(agg + (size_t)N_NODES * 64);  // N*64 bf16
    float*          dinv     = (float*)(tb + (size_t)N_NODES * 64);            // N
    float*          stats    = dinv + N_NODES;                     // 128
    int*            cnt      = (int*)(stats + 128);                // N
    int*            row_off  = cnt + N_NODES;                      // N+1
    int*            cursor   = row_off + N_NODES + 1;              // N
    int*            blocksum = cursor + N_NODES;                   // 98 (+pad)
    int*            csr_src  = blocksum + 128;                     // E

    const int* srcp = eidx;
    const int* dstp = eidx + N_EDGES;

    // CSR build (by destination) + dinv
    hipMemsetAsync(cnt, 0, N_NODES * sizeof(int), stream);
    hipMemsetAsync(cursor, 0, N_NODES * sizeof(int), stream);
    hist_kernel<<<(N_EDGES + 255) / 256, 256, 0, stream>>>(dstp, cnt);
    scan_phase1<<<N_SCAN_BLOCKS, 256, 0, stream>>>(cnt, blocksum);
    scan_phase2<<<1, 128, 0, stream>>>(blocksum);
    scan_phase3<<<N_SCAN_BLOCKS, 256, 0, stream>>>(cnt, blocksum, row_off, dinv);
    fill_bucketed<<<FILL_CHUNKS * N_XCD, 256, 0, stream>>>(srcp, dstp, row_off, cursor, csr_src);

    const int gemm_grid = (N_NODES + 15) / 16;

    // layer 1
    gemm_l0<<<gemm_grid, 256, 0, stream>>>(x, W[0], dinv, tb);
    hipMemsetAsync(stats, 0, 128 * sizeof(float), stream);
    gather_agg<<<2048, 256, 0, stream>>>(csr_src, row_off, dinv, tb, b[0], agg, stats);

    // layer 2
    bn_gemm<<<gemm_grid, 256, 0, stream>>>(agg, stats, gm[0], be[0], W[1], dinv, tb);
    hipMemsetAsync(stats, 0, 128 * sizeof(float), stream);
    gather_agg<<<2048, 256, 0, stream>>>(csr_src, row_off, dinv, tb, b[1], agg, stats);

    // layer 3
    bn_gemm<<<gemm_grid, 256, 0, stream>>>(agg, stats, gm[1], be[1], W[2], dinv, tb);
    hipMemsetAsync(stats, 0, 128 * sizeof(float), stream);
    gather_agg<<<2048, 256, 0, stream>>>(csr_src, row_off, dinv, tb, b[2], agg, stats);

    // pool with inline BN3
    pool_bn<<<N_GRAPHS, 256, 0, stream>>>(agg, batch, stats, gm[2], be[2], (float*)d_out);
}

// Round 5
// 602.589 us; speedup vs baseline: 2.4715x; 1.0192x over previous
//
#include <hip/hip_runtime.h>
#include <hip/hip_bf16.h>
#include <math.h>

#define N_NODES 100000
#define N_EDGES 1600000
#define DIM 64
#define N_GRAPHS 256
#define BN_EPS 1e-5f
#define SCAN_BLOCK 1024
#define N_SCAN_BLOCKS ((N_NODES + SCAN_BLOCK - 1) / SCAN_BLOCK)   // 98
#define N_XCD 8
#define BUCKET ((N_NODES + N_XCD - 1) / N_XCD)                    // 12500
#define FILL_CHUNKS 128
#define FILL_ESIZE ((N_EDGES + FILL_CHUNKS - 1) / FILL_CHUNKS)    // 12500

__device__ inline unsigned short f2bf(float f) {
    __hip_bfloat16 h = __float2bfloat16(f);   // RNE
    return *reinterpret_cast<unsigned short*>(&h);
}
__device__ inline unsigned int pack2bf(float a, float b) {
    return (unsigned int)f2bf(a) | ((unsigned int)f2bf(b) << 16);
}
__device__ inline float bf_lo(unsigned int u) { return __uint_as_float(u << 16); }
__device__ inline float bf_hi(unsigned int u) { return __uint_as_float(u & 0xffff0000u); }

// ---------------- CSR build ----------------
// hist + rank: the atomic's old value IS this edge's slot within its dst row.
__global__ void hist_rank(const int* __restrict__ dst, int* __restrict__ cnt,
                          unsigned short* __restrict__ rank) {
    int e = blockIdx.x * blockDim.x + threadIdx.x;
    if (e < N_EDGES) {
        int d = __builtin_nontemporal_load(&dst[e]);
        int r = atomicAdd(&cnt[d], 1);
        rank[e] = (unsigned short)r;
    }
}

__global__ __launch_bounds__(256) void scan_phase1(const int* __restrict__ cnt,
                                                   int* __restrict__ blocksums) {
    __shared__ int sh[256];
    int tid = threadIdx.x;
    int base = blockIdx.x * SCAN_BLOCK + tid * 4;
    int s = 0;
    if (base + 3 < N_NODES) {
        int4 c = *reinterpret_cast<const int4*>(cnt + base);
        s = c.x + c.y + c.z + c.w;
    } else {
        for (int i = 0; i < 4; ++i) if (base + i < N_NODES) s += cnt[base + i];
    }
    sh[tid] = s;
    __syncthreads();
    for (int off = 128; off > 0; off >>= 1) {
        if (tid < off) sh[tid] += sh[tid + off];
        __syncthreads();
    }
    if (tid == 0) blocksums[blockIdx.x] = sh[0];
}

__global__ __launch_bounds__(128) void scan_phase2(int* __restrict__ blocksums) {
    __shared__ int sh[128];
    int tid = threadIdx.x;
    int v = (tid < N_SCAN_BLOCKS) ? blocksums[tid] : 0;
    sh[tid] = v;
    __syncthreads();
    for (int off = 1; off < 128; off <<= 1) {
        int u = (tid >= off) ? sh[tid - off] : 0;
        __syncthreads();
        sh[tid] += u;
        __syncthreads();
    }
    if (tid < N_SCAN_BLOCKS) blocksums[tid] = sh[tid] - v;   // exclusive
}

__global__ __launch_bounds__(256) void scan_phase3(const int* __restrict__ cnt,
                                                   const int* __restrict__ blocksums,
                                                   int* __restrict__ row_off,
                                                   float* __restrict__ dinv) {
    __shared__ int sh[256];
    int tid = threadIdx.x;
    int base = blockIdx.x * SCAN_BLOCK + tid * 4;
    int c0 = 0, c1 = 0, c2 = 0, c3 = 0;
    if (base + 3 < N_NODES) {
        int4 cc = *reinterpret_cast<const int4*>(cnt + base);
        c0 = cc.x; c1 = cc.y; c2 = cc.z; c3 = cc.w;
    } else {
        if (base + 0 < N_NODES) c0 = cnt[base + 0];
        if (base + 1 < N_NODES) c1 = cnt[base + 1];
        if (base + 2 < N_NODES) c2 = cnt[base + 2];
        if (base + 3 < N_NODES) c3 = cnt[base + 3];
    }
    int mysum = c0 + c1 + c2 + c3;
    sh[tid] = mysum;
    __syncthreads();
    for (int off = 1; off < 256; off <<= 1) {
        int u = (tid >= off) ? sh[tid - off] : 0;
        __syncthreads();
        sh[tid] += u;
        __syncthreads();
    }
    int prefix = blocksums[blockIdx.x] + sh[tid] - mysum;
    int c[4] = {c0, c1, c2, c3};
    for (int i = 0; i < 4; ++i) {
        int idx = base + i;
        if (idx < N_NODES) {
            row_off[idx] = prefix;
            prefix += c[i];
            dinv[idx] = rsqrtf((float)(c[i] + 1));   // self loop included
        }
    }
    if (blockIdx.x == 0 && tid == 0) row_off[N_NODES] = N_EDGES;
}

// XCD-bucketed fill, atomic-free: pos = row_off[d] + rank[e].
// Streaming reads are nontemporal so they don't evict the resident csr lines.
__global__ __launch_bounds__(256) void fill_bucketed(const int* __restrict__ src,
                                                     const int* __restrict__ dst,
                                                     const int* __restrict__ row_off,
                                                     const unsigned short* __restrict__ rank,
                                                     int* __restrict__ csr_src) {
    int chunk = blockIdx.x >> 3;
    int lo = (blockIdx.x & (N_XCD - 1)) * BUCKET;
    int e0 = chunk * FILL_ESIZE;
    int e1 = min(e0 + FILL_ESIZE, N_EDGES);
    for (int e = e0 + threadIdx.x; e < e1; e += 256) {
        int d = __builtin_nontemporal_load(&dst[e]);
        if ((unsigned)(d - lo) < (unsigned)BUCKET) {
            int pos = row_off[d] + (int)__builtin_nontemporal_load(&rank[e]);
            csr_src[pos] = __builtin_nontemporal_load(&src[e]);
        }
    }
}

// ---------------- layer-0 GEMM: t = bf16(dinv[row] * (x @ W)) ----------------
__global__ __launch_bounds__(256) void gemm_l0(const float* __restrict__ h,
                                               const float* __restrict__ W,
                                               const float* __restrict__ dinv,
                                               unsigned short* __restrict__ tb) {
    __shared__ float Ws[64 * 64];
    int tid = threadIdx.x;
    #pragma unroll
    for (int i = 0; i < 16; ++i) Ws[i * 256 + tid] = W[i * 256 + tid];
    __syncthreads();
    int d = tid & 63, g = tid >> 6;
    int row0 = blockIdx.x * 16 + g * 4;
    #pragma unroll
    for (int r = 0; r < 4; ++r) {
        int row = row0 + r;
        if (row >= N_NODES) return;
        const float4* hv = reinterpret_cast<const float4*>(h + (size_t)row * 64);
        float acc = 0.f;
        #pragma unroll
        for (int k4 = 0; k4 < 16; ++k4) {
            float4 hk = hv[k4];
            acc = fmaf(hk.x, Ws[(k4 * 4 + 0) * 64 + d], acc);
            acc = fmaf(hk.y, Ws[(k4 * 4 + 1) * 64 + d], acc);
            acc = fmaf(hk.z, Ws[(k4 * 4 + 2) * 64 + d], acc);
            acc = fmaf(hk.w, Ws[(k4 * 4 + 3) * 64 + d], acc);
        }
        tb[(size_t)row * 64 + d] = f2bf(acc * dinv[row]);
    }
}

// ------- fused BN + ReLU + GEMM over bf16 h: t = bf16(dinv[row]*(bnrelu(h) @ W)) -------
__global__ __launch_bounds__(256) void bn_gemm(const unsigned short* __restrict__ hb,
                                               const float* __restrict__ stats,
                                               const float* __restrict__ gamma,
                                               const float* __restrict__ beta,
                                               const float* __restrict__ W,
                                               const float* __restrict__ dinv,
                                               unsigned short* __restrict__ tb) {
    __shared__ float Ws[64 * 64];
    __shared__ float scale[64], shift[64];
    int tid = threadIdx.x;
    #pragma unroll
    for (int i = 0; i < 16; ++i) Ws[i * 256 + tid] = W[i * 256 + tid];
    if (tid < 64) {
        const float inv_n = 1.0f / (float)N_NODES;
        float mean = stats[tid] * inv_n;
        float var = fmaxf(stats[64 + tid] * inv_n - mean * mean, 0.f);
        float rs = rsqrtf(var + BN_EPS) * gamma[tid];
        scale[tid] = rs;
        shift[tid] = beta[tid] - mean * rs;
    }
    __syncthreads();
    int d = tid & 63, g = tid >> 6;
    int row0 = blockIdx.x * 16 + g * 4;
    #pragma unroll
    for (int r = 0; r < 4; ++r) {
        int row = row0 + r;
        if (row >= N_NODES) return;
        const uint2* hv = reinterpret_cast<const uint2*>(hb + (size_t)row * 64);
        float acc = 0.f;
        #pragma unroll
        for (int c = 0; c < 16; ++c) {
            uint2 u = hv[c];
            int k = c * 4;
            float a0 = fmaxf(fmaf(bf_lo(u.x), scale[k + 0], shift[k + 0]), 0.f);
            float a1 = fmaxf(fmaf(bf_hi(u.x), scale[k + 1], shift[k + 1]), 0.f);
            float a2 = fmaxf(fmaf(bf_lo(u.y), scale[k + 2], shift[k + 2]), 0.f);
            float a3 = fmaxf(fmaf(bf_hi(u.y), scale[k + 3], shift[k + 3]), 0.f);
            acc = fmaf(a0, Ws[(k + 0) * 64 + d], acc);
            acc = fmaf(a1, Ws[(k + 1) * 64 + d], acc);
            acc = fmaf(a2, Ws[(k + 2) * 64 + d], acc);
            acc = fmaf(a3, Ws[(k + 3) * 64 + d], acc);
        }
        tb[(size_t)row * 64 + d] = f2bf(acc * dinv[row]);
    }
}

// ------- CSR segment gather over bf16 t; quarter-per-edge, unroll x4 -------
__global__ __launch_bounds__(256) void gather_agg(const int* __restrict__ csr_src,
                                                  const int* __restrict__ row_off,
                                                  const float* __restrict__ dinv,
                                                  const unsigned short* __restrict__ tb,
                                                  const float* __restrict__ bias,
                                                  unsigned short* __restrict__ out,
                                                  float* __restrict__ stats) {
    int tid = threadIdx.x;
    int wave = tid >> 6;
    int lane = tid & 63;
    int q    = lane >> 4;        // quarter 0..3 -> edge slot offset
    int ql   = lane & 15;        // columns ql*4 .. ql*4+3

    float4 s4  = {0.f, 0.f, 0.f, 0.f};
    float4 sq4 = {0.f, 0.f, 0.f, 0.f};

    for (int v = blockIdx.x * 4 + wave; v < N_NODES; v += gridDim.x * 4) {
        int beg = row_off[v], end = row_off[v + 1];
        float4 A0 = {0,0,0,0}, A1 = {0,0,0,0}, A2 = {0,0,0,0}, A3 = {0,0,0,0};
        int e = beg + q;
        for (; e + 12 < end; e += 16) {
            int s0 = csr_src[e];
            int s1 = csr_src[e + 4];
            int s2 = csr_src[e + 8];
            int s3 = csr_src[e + 12];
            uint2 u0 = *reinterpret_cast<const uint2*>(tb + (size_t)s0 * 64 + ql * 4);
            uint2 u1 = *reinterpret_cast<const uint2*>(tb + (size_t)s1 * 64 + ql * 4);
            uint2 u2 = *reinterpret_cast<const uint2*>(tb + (size_t)s2 * 64 + ql * 4);
            uint2 u3 = *reinterpret_cast<const uint2*>(tb + (size_t)s3 * 64 + ql * 4);
            A0.x += bf_lo(u0.x); A0.y += bf_hi(u0.x); A0.z += bf_lo(u0.y); A0.w += bf_hi(u0.y);
            A1.x += bf_lo(u1.x); A1.y += bf_hi(u1.x); A1.z += bf_lo(u1.y); A1.w += bf_hi(u1.y);
            A2.x += bf_lo(u2.x); A2.y += bf_hi(u2.x); A2.z += bf_lo(u2.y); A2.w += bf_hi(u2.y);
            A3.x += bf_lo(u3.x); A3.y += bf_hi(u3.x); A3.z += bf_lo(u3.y); A3.w += bf_hi(u3.y);
        }
        for (; e < end; e += 4) {
            int s0 = csr_src[e];
            uint2 u0 = *reinterpret_cast<const uint2*>(tb + (size_t)s0 * 64 + ql * 4);
            A0.x += bf_lo(u0.x); A0.y += bf_hi(u0.x); A0.z += bf_lo(u0.y); A0.w += bf_hi(u0.y);
        }
        float4 acc;
        acc.x = (A0.x + A1.x) + (A2.x + A3.x);
        acc.y = (A0.y + A1.y) + (A2.y + A3.y);
        acc.z = (A0.z + A1.z) + (A2.z + A3.z);
        acc.w = (A0.w + A1.w) + (A2.w + A3.w);

        acc.x += __shfl_xor(acc.x, 16, 64); acc.x += __shfl_xor(acc.x, 32, 64);
        acc.y += __shfl_xor(acc.y, 16, 64); acc.y += __shfl_xor(acc.y, 32, 64);
        acc.z += __shfl_xor(acc.z, 16, 64); acc.z += __shfl_xor(acc.z, 32, 64);
        acc.w += __shfl_xor(acc.w, 16, 64); acc.w += __shfl_xor(acc.w, 32, 64);

        if (q == 0) {
            float di = dinv[v];
            uint2 uv = *reinterpret_cast<const uint2*>(tb + (size_t)v * 64 + ql * 4);
            float4 bi = *reinterpret_cast<const float4*>(bias + ql * 4);
            float4 val;
            val.x = fmaf(di, acc.x + bf_lo(uv.x), bi.x);
            val.y = fmaf(di, acc.y + bf_hi(uv.x), bi.y);
            val.z = fmaf(di, acc.z + bf_lo(uv.y), bi.z);
            val.w = fmaf(di, acc.w + bf_hi(uv.y), bi.w);
            uint2 o;
            o.x = pack2bf(val.x, val.y);
            o.y = pack2bf(val.z, val.w);
            *reinterpret_cast<uint2*>(out + (size_t)v * 64 + ql * 4) = o;
            s4.x += val.x; s4.y += val.y; s4.z += val.z; s4.w += val.w;
            sq4.x += val.x * val.x; sq4.y += val.y * val.y;
            sq4.z += val.z * val.z; sq4.w += val.w * val.w;
        }
    }

    __shared__ float shs[4][64];
    __shared__ float shq[4][64];
    if (q == 0) {
        *reinterpret_cast<float4*>(&shs[wave][ql * 4]) = s4;
        *reinterpret_cast<float4*>(&shq[wave][ql * 4]) = sq4;
    }
    __syncthreads();
    if (tid < 64) {
        float S = shs[0][tid] + shs[1][tid] + shs[2][tid] + shs[3][tid];
        float Q = shq[0][tid] + shq[1][tid] + shq[2][tid] + shq[3][tid];
        unsafeAtomicAdd(&stats[tid], S);
        unsafeAtomicAdd(&stats[64 + tid], Q);
    }
}

// ---------------- per-graph mean+max pool with inline final BN (bf16 h) ----------------
__global__ __launch_bounds__(256) void pool_bn(const unsigned short* __restrict__ hb,
                                               const int* __restrict__ batch,
                                               const float* __restrict__ stats,
                                               const float* __restrict__ gamma,
                                               const float* __restrict__ beta,
                                               float* __restrict__ out) {
    __shared__ float scale[64], shift[64];
    __shared__ int bounds[2];
    int tid = threadIdx.x;
    if (tid < 64) {
        const float inv_n = 1.0f / (float)N_NODES;
        float mean = stats[tid] * inv_n;
        float var = fmaxf(stats[64 + tid] * inv_n - mean * mean, 0.f);
        float rs = rsqrtf(var + BN_EPS) * gamma[tid];
        scale[tid] = rs;
        shift[tid] = beta[tid] - mean * rs;
    }
    if (tid < 2) {
        int target = blockIdx.x + tid;
        int lo = 0, hi = N_NODES;
        while (lo < hi) {
            int mid = (lo + hi) >> 1;
            if (batch[mid] < target) lo = mid + 1; else hi = mid;
        }
        bounds[tid] = lo;
    }
    __syncthreads();
    int lo = bounds[0], hi = bounds[1];
    int d = tid & 63, g = tid >> 6;
    float s = 0.f, m = -3.402823466e38f;
    for (int row = lo + g; row < hi; row += 4) {
        float v = __uint_as_float(((unsigned int)hb[(size_t)row * 64 + d]) << 16);
        v = fmaf(v, scale[d], shift[d]);
        s += v;
        m = fmaxf(m, v);
    }
    __shared__ float sh[8][64];
    sh[g][d] = s;
    sh[4 + g][d] = m;
    __syncthreads();
    if (tid < 64) {
        float S = sh[0][tid] + sh[1][tid] + sh[2][tid] + sh[3][tid];
        float M = fmaxf(fmaxf(sh[4][tid], sh[5][tid]), fmaxf(sh[6][tid], sh[7][tid]));
        int cnt = hi - lo;
        float mean = S / fmaxf((float)cnt, 1.0f);
        float mx = (cnt > 0) ? M : 0.0f;
        out[blockIdx.x * 64 + tid] = mean + mx;
    }
}

extern "C" void kernel_launch(void* const* d_in, const int* in_sizes, int n_in,
                              void* d_out, int out_size, void* d_ws, size_t ws_size,
                              hipStream_t stream) {
    const float* x     = (const float*)d_in[0];
    const int*   eidx  = (const int*)d_in[1];
    const int*   batch = (const int*)d_in[2];
    const float* W[3]  = {(const float*)d_in[3], (const float*)d_in[7],  (const float*)d_in[11]};
    const float* b[3]  = {(const float*)d_in[4], (const float*)d_in[8],  (const float*)d_in[12]};
    const float* gm[3] = {(const float*)d_in[5], (const float*)d_in[9],  (const float*)d_in[13]};
    const float* be[3] = {(const float*)d_in[6], (const float*)d_in[10], (const float*)d_in[14]};

    unsigned short* agg   = (unsigned short*)d_ws;                      // N*64 bf16
    unsigned short* tb    = agg + (size_t)N_NODES * 64;                 // N*64 bf16
    unsigned short* rank  = tb + (size_t)N_NODES * 64;                  // E
    float* dinv     = (float*)(rank + N_EDGES);                         // N
    float* stats    = dinv + N_NODES;                                   // 3*128
    int*   cnt      = (int*)(stats + 384);                              // N
    int*   row_off  = cnt + N_NODES;                                    // N+1
    int*   blocksum = row_off + N_NODES + 1;                            // 128
    int*   csr_src  = blocksum + 128;                                   // E

    const int* srcp = eidx;
    const int* dstp = eidx + N_EDGES;

    // one memset covers all 3 stats slots + cnt (contiguous)
    hipMemsetAsync(stats, 0, (384 + N_NODES) * sizeof(float), stream);

    // CSR build (by destination) + dinv, atomic-free fill via rank
    hist_rank<<<(N_EDGES + 255) / 256, 256, 0, stream>>>(dstp, cnt, rank);
    scan_phase1<<<N_SCAN_BLOCKS, 256, 0, stream>>>(cnt, blocksum);
    scan_phase2<<<1, 128, 0, stream>>>(blocksum);
    scan_phase3<<<N_SCAN_BLOCKS, 256, 0, stream>>>(cnt, blocksum, row_off, dinv);
    fill_bucketed<<<FILL_CHUNKS * N_XCD, 256, 0, stream>>>(srcp, dstp, row_off, rank, csr_src);

    const int gemm_grid = (N_NODES + 15) / 16;

    // layer 1
    gemm_l0<<<gemm_grid, 256, 0, stream>>>(x, W[0], dinv, tb);
    gather_agg<<<2048, 256, 0, stream>>>(csr_src, row_off, dinv, tb, b[0], agg, stats);

    // layer 2
    bn_gemm<<<gemm_grid, 256, 0, stream>>>(agg, stats, gm[0], be[0], W[1], dinv, tb);
    gather_agg<<<2048, 256, 0, stream>>>(csr_src, row_off, dinv, tb, b[1], agg, stats + 128);

    // layer 3
    bn_gemm<<<gemm_grid, 256, 0, stream>>>(agg, stats + 128, gm[1], be[1], W[2], dinv, tb);
    gather_agg<<<2048, 256, 0, stream>>>(csr_src, row_off, dinv, tb, b[2], agg, stats + 256);

    // pool with inline BN3
    pool_bn<<<N_GRAPHS, 256, 0, stream>>>(agg, batch, stats + 256, gm[2], be[2], (float*)d_out);
}

// Round 6
// 544.372 us; speedup vs baseline: 2.7359x; 1.1069x over previous
//
#include <hip/hip_runtime.h>
#include <hip/hip_bf16.h>
#include <math.h>

#define N_NODES 100000
#define N_EDGES 1600000
#define DIM 64
#define N_GRAPHS 256
#define BN_EPS 1e-5f
#define SCAN_BLOCK 1024
#define N_SCAN_BLOCKS ((N_NODES + SCAN_BLOCK - 1) / SCAN_BLOCK)   // 98
#define N_XCD 8
#define BUCKET ((N_NODES + N_XCD - 1) / N_XCD)                    // 12500
#define FILL_CHUNKS 128
#define FILL_ESIZE ((N_EDGES + FILL_CHUNKS - 1) / FILL_CHUNKS)    // 12500

__device__ inline unsigned short f2bf(float f) {
    __hip_bfloat16 h = __float2bfloat16(f);   // RNE
    return *reinterpret_cast<unsigned short*>(&h);
}
__device__ inline unsigned int pack2bf(float a, float b) {
    return (unsigned int)f2bf(a) | ((unsigned int)f2bf(b) << 16);
}
__device__ inline float bf_lo(unsigned int u) { return __uint_as_float(u << 16); }
__device__ inline float bf_hi(unsigned int u) { return __uint_as_float(u & 0xffff0000u); }

// ---------------- CSR build ----------------
__global__ void hist_rank(const int* __restrict__ dst, int* __restrict__ cnt,
                          unsigned short* __restrict__ rank) {
    int e = blockIdx.x * blockDim.x + threadIdx.x;
    if (e < N_EDGES) {
        int d = __builtin_nontemporal_load(&dst[e]);
        int r = atomicAdd(&cnt[d], 1);
        rank[e] = (unsigned short)r;
    }
}

__global__ __launch_bounds__(256) void scan_phase1(const int* __restrict__ cnt,
                                                   int* __restrict__ blocksums) {
    __shared__ int sh[256];
    int tid = threadIdx.x;
    int base = blockIdx.x * SCAN_BLOCK + tid * 4;
    int s = 0;
    if (base + 3 < N_NODES) {
        int4 c = *reinterpret_cast<const int4*>(cnt + base);
        s = c.x + c.y + c.z + c.w;
    } else {
        for (int i = 0; i < 4; ++i) if (base + i < N_NODES) s += cnt[base + i];
    }
    sh[tid] = s;
    __syncthreads();
    for (int off = 128; off > 0; off >>= 1) {
        if (tid < off) sh[tid] += sh[tid + off];
        __syncthreads();
    }
    if (tid == 0) blocksums[blockIdx.x] = sh[0];
}

__global__ __launch_bounds__(128) void scan_phase2(int* __restrict__ blocksums) {
    __shared__ int sh[128];
    int tid = threadIdx.x;
    int v = (tid < N_SCAN_BLOCKS) ? blocksums[tid] : 0;
    sh[tid] = v;
    __syncthreads();
    for (int off = 1; off < 128; off <<= 1) {
        int u = (tid >= off) ? sh[tid - off] : 0;
        __syncthreads();
        sh[tid] += u;
        __syncthreads();
    }
    if (tid < N_SCAN_BLOCKS) blocksums[tid] = sh[tid] - v;   // exclusive
}

__global__ __launch_bounds__(256) void scan_phase3(const int* __restrict__ cnt,
                                                   const int* __restrict__ blocksums,
                                                   int* __restrict__ row_off,
                                                   float* __restrict__ dinv) {
    __shared__ int sh[256];
    int tid = threadIdx.x;
    int base = blockIdx.x * SCAN_BLOCK + tid * 4;
    int c0 = 0, c1 = 0, c2 = 0, c3 = 0;
    if (base + 3 < N_NODES) {
        int4 cc = *reinterpret_cast<const int4*>(cnt + base);
        c0 = cc.x; c1 = cc.y; c2 = cc.z; c3 = cc.w;
    } else {
        if (base + 0 < N_NODES) c0 = cnt[base + 0];
        if (base + 1 < N_NODES) c1 = cnt[base + 1];
        if (base + 2 < N_NODES) c2 = cnt[base + 2];
        if (base + 3 < N_NODES) c3 = cnt[base + 3];
    }
    int mysum = c0 + c1 + c2 + c3;
    sh[tid] = mysum;
    __syncthreads();
    for (int off = 1; off < 256; off <<= 1) {
        int u = (tid >= off) ? sh[tid - off] : 0;
        __syncthreads();
        sh[tid] += u;
        __syncthreads();
    }
    int prefix = blocksums[blockIdx.x] + sh[tid] - mysum;
    int c[4] = {c0, c1, c2, c3};
    for (int i = 0; i < 4; ++i) {
        int idx = base + i;
        if (idx < N_NODES) {
            row_off[idx] = prefix;
            prefix += c[i];
            dinv[idx] = rsqrtf((float)(c[i] + 1));   // self loop included
        }
    }
    if (blockIdx.x == 0 && tid == 0) row_off[N_NODES] = N_EDGES;
}

__global__ __launch_bounds__(256) void fill_bucketed(const int* __restrict__ src,
                                                     const int* __restrict__ dst,
                                                     const int* __restrict__ row_off,
                                                     const unsigned short* __restrict__ rank,
                                                     int* __restrict__ csr_src) {
    int chunk = blockIdx.x >> 3;
    int lo = (blockIdx.x & (N_XCD - 1)) * BUCKET;
    int e0 = chunk * FILL_ESIZE;
    int e1 = min(e0 + FILL_ESIZE, N_EDGES);
    for (int e = e0 + threadIdx.x; e < e1; e += 256) {
        int d = __builtin_nontemporal_load(&dst[e]);
        if ((unsigned)(d - lo) < (unsigned)BUCKET) {
            int pos = row_off[d] + (int)__builtin_nontemporal_load(&rank[e]);
            csr_src[pos] = __builtin_nontemporal_load(&src[e]);
        }
    }
}

// ---- scalar-broadcast GEMM: t = bf16(dinv[row] * (h @ W)), h f32 ----
// W column d lives in 64 VGPRs; h row address is wave-uniform -> SGPR loads;
// inner loop is pure v_fma_f32 (sgpr, vgpr) with 4 acc chains. No LDS.
__global__ __launch_bounds__(256) void gemm_f32(const float* __restrict__ h,
                                                const float* __restrict__ W,
                                                const float* __restrict__ dinv,
                                                unsigned short* __restrict__ tb) {
    int tid = threadIdx.x;
    int d = tid & 63;
    int wv = tid >> 6;
    float wcol[64];
    #pragma unroll
    for (int k = 0; k < 64; ++k) wcol[k] = W[k * 64 + d];   // coalesced, L2-hot
    int nwaves = gridDim.x * 4;
    for (int row = blockIdx.x * 4 + wv; row < N_NODES; row += nwaves) {
        int urow = __builtin_amdgcn_readfirstlane(row);
        const float* hr = h + (size_t)urow * 64;
        float a0 = 0.f, a1 = 0.f, a2 = 0.f, a3 = 0.f;
        #pragma unroll
        for (int k = 0; k < 64; k += 4) {
            a0 = fmaf(hr[k + 0], wcol[k + 0], a0);
            a1 = fmaf(hr[k + 1], wcol[k + 1], a1);
            a2 = fmaf(hr[k + 2], wcol[k + 2], a2);
            a3 = fmaf(hr[k + 3], wcol[k + 3], a3);
        }
        float acc = (a0 + a1) + (a2 + a3);
        tb[(size_t)urow * 64 + d] = f2bf(acc * dinv[urow]);
    }
}

// ---- elementwise BN+ReLU: hp = relu(scale*agg + shift), bf16 -> f32 ----
__global__ __launch_bounds__(256) void bnrelu(const unsigned short* __restrict__ agg,
                                              const float* __restrict__ stats,
                                              const float* __restrict__ gamma,
                                              const float* __restrict__ beta,
                                              float* __restrict__ hp) {
    __shared__ float scale[64], shift[64];
    int tid = threadIdx.x;
    if (tid < 64) {
        const float inv_n = 1.0f / (float)N_NODES;
        float mean = stats[tid] * inv_n;
        float var = fmaxf(stats[64 + tid] * inv_n - mean * mean, 0.f);
        float rs = rsqrtf(var + BN_EPS) * gamma[tid];
        scale[tid] = rs;
        shift[tid] = beta[tid] - mean * rs;
    }
    __syncthreads();
    const size_t total = (size_t)N_NODES * 8;   // groups of 8 bf16
    for (size_t i = (size_t)blockIdx.x * 256 + tid; i < total; i += (size_t)gridDim.x * 256) {
        uint4 u = *reinterpret_cast<const uint4*>(agg + i * 8);
        int dd = (int)((i * 8) & 63);
        float4 o0, o1;
        o0.x = fmaxf(fmaf(bf_lo(u.x), scale[dd + 0], shift[dd + 0]), 0.f);
        o0.y = fmaxf(fmaf(bf_hi(u.x), scale[dd + 1], shift[dd + 1]), 0.f);
        o0.z = fmaxf(fmaf(bf_lo(u.y), scale[dd + 2], shift[dd + 2]), 0.f);
        o0.w = fmaxf(fmaf(bf_hi(u.y), scale[dd + 3], shift[dd + 3]), 0.f);
        o1.x = fmaxf(fmaf(bf_lo(u.z), scale[dd + 4], shift[dd + 4]), 0.f);
        o1.y = fmaxf(fmaf(bf_hi(u.z), scale[dd + 5], shift[dd + 5]), 0.f);
        o1.z = fmaxf(fmaf(bf_lo(u.w), scale[dd + 6], shift[dd + 6]), 0.f);
        o1.w = fmaxf(fmaf(bf_hi(u.w), scale[dd + 7], shift[dd + 7]), 0.f);
        *reinterpret_cast<float4*>(hp + i * 8) = o0;
        *reinterpret_cast<float4*>(hp + i * 8 + 4) = o1;
    }
}

// ------- CSR segment gather over bf16 t; quarter-per-edge, unroll x4 -------
__global__ __launch_bounds__(256) void gather_agg(const int* __restrict__ csr_src,
                                                  const int* __restrict__ row_off,
                                                  const float* __restrict__ dinv,
                                                  const unsigned short* __restrict__ tb,
                                                  const float* __restrict__ bias,
                                                  unsigned short* __restrict__ out,
                                                  float* __restrict__ stats) {
    int tid = threadIdx.x;
    int wave = tid >> 6;
    int lane = tid & 63;
    int q    = lane >> 4;
    int ql   = lane & 15;

    float4 s4  = {0.f, 0.f, 0.f, 0.f};
    float4 sq4 = {0.f, 0.f, 0.f, 0.f};

    for (int v = blockIdx.x * 4 + wave; v < N_NODES; v += gridDim.x * 4) {
        int beg = row_off[v], end = row_off[v + 1];
        float4 A0 = {0,0,0,0}, A1 = {0,0,0,0}, A2 = {0,0,0,0}, A3 = {0,0,0,0};
        int e = beg + q;
        for (; e + 12 < end; e += 16) {
            int s0 = csr_src[e];
            int s1 = csr_src[e + 4];
            int s2 = csr_src[e + 8];
            int s3 = csr_src[e + 12];
            uint2 u0 = *reinterpret_cast<const uint2*>(tb + (size_t)s0 * 64 + ql * 4);
            uint2 u1 = *reinterpret_cast<const uint2*>(tb + (size_t)s1 * 64 + ql * 4);
            uint2 u2 = *reinterpret_cast<const uint2*>(tb + (size_t)s2 * 64 + ql * 4);
            uint2 u3 = *reinterpret_cast<const uint2*>(tb + (size_t)s3 * 64 + ql * 4);
            A0.x += bf_lo(u0.x); A0.y += bf_hi(u0.x); A0.z += bf_lo(u0.y); A0.w += bf_hi(u0.y);
            A1.x += bf_lo(u1.x); A1.y += bf_hi(u1.x); A1.z += bf_lo(u1.y); A1.w += bf_hi(u1.y);
            A2.x += bf_lo(u2.x); A2.y += bf_hi(u2.x); A2.z += bf_lo(u2.y); A2.w += bf_hi(u2.y);
            A3.x += bf_lo(u3.x); A3.y += bf_hi(u3.x); A3.z += bf_lo(u3.y); A3.w += bf_hi(u3.y);
        }
        for (; e < end; e += 4) {
            int s0 = csr_src[e];
            uint2 u0 = *reinterpret_cast<const uint2*>(tb + (size_t)s0 * 64 + ql * 4);
            A0.x += bf_lo(u0.x); A0.y += bf_hi(u0.x); A0.z += bf_lo(u0.y); A0.w += bf_hi(u0.y);
        }
        float4 acc;
        acc.x = (A0.x + A1.x) + (A2.x + A3.x);
        acc.y = (A0.y + A1.y) + (A2.y + A3.y);
        acc.z = (A0.z + A1.z) + (A2.z + A3.z);
        acc.w = (A0.w + A1.w) + (A2.w + A3.w);

        acc.x += __shfl_xor(acc.x, 16, 64); acc.x += __shfl_xor(acc.x, 32, 64);
        acc.y += __shfl_xor(acc.y, 16, 64); acc.y += __shfl_xor(acc.y, 32, 64);
        acc.z += __shfl_xor(acc.z, 16, 64); acc.z += __shfl_xor(acc.z, 32, 64);
        acc.w += __shfl_xor(acc.w, 16, 64); acc.w += __shfl_xor(acc.w, 32, 64);

        if (q == 0) {
            float di = dinv[v];
            uint2 uv = *reinterpret_cast<const uint2*>(tb + (size_t)v * 64 + ql * 4);
            float4 bi = *reinterpret_cast<const float4*>(bias + ql * 4);
            float4 val;
            val.x = fmaf(di, acc.x + bf_lo(uv.x), bi.x);
            val.y = fmaf(di, acc.y + bf_hi(uv.x), bi.y);
            val.z = fmaf(di, acc.z + bf_lo(uv.y), bi.z);
            val.w = fmaf(di, acc.w + bf_hi(uv.y), bi.w);
            uint2 o;
            o.x = pack2bf(val.x, val.y);
            o.y = pack2bf(val.z, val.w);
            *reinterpret_cast<uint2*>(out + (size_t)v * 64 + ql * 4) = o;
            s4.x += val.x; s4.y += val.y; s4.z += val.z; s4.w += val.w;
            sq4.x += val.x * val.x; sq4.y += val.y * val.y;
            sq4.z += val.z * val.z; sq4.w += val.w * val.w;
        }
    }

    __shared__ float shs[4][64];
    __shared__ float shq[4][64];
    if (q == 0) {
        *reinterpret_cast<float4*>(&shs[wave][ql * 4]) = s4;
        *reinterpret_cast<float4*>(&shq[wave][ql * 4]) = sq4;
    }
    __syncthreads();
    if (tid < 64) {
        float S = shs[0][tid] + shs[1][tid] + shs[2][tid] + shs[3][tid];
        float Q = shq[0][tid] + shq[1][tid] + shq[2][tid] + shq[3][tid];
        unsafeAtomicAdd(&stats[tid], S);
        unsafeAtomicAdd(&stats[64 + tid], Q);
    }
}

// ---------------- per-graph mean+max pool with inline final BN (bf16 h) ----------------
__global__ __launch_bounds__(256) void pool_bn(const unsigned short* __restrict__ hb,
                                               const int* __restrict__ batch,
                                               const float* __restrict__ stats,
                                               const float* __restrict__ gamma,
                                               const float* __restrict__ beta,
                                               float* __restrict__ out) {
    __shared__ float scale[64], shift[64];
    __shared__ int bounds[2];
    int tid = threadIdx.x;
    if (tid < 64) {
        const float inv_n = 1.0f / (float)N_NODES;
        float mean = stats[tid] * inv_n;
        float var = fmaxf(stats[64 + tid] * inv_n - mean * mean, 0.f);
        float rs = rsqrtf(var + BN_EPS) * gamma[tid];
        scale[tid] = rs;
        shift[tid] = beta[tid] - mean * rs;
    }
    if (tid < 2) {
        int target = blockIdx.x + tid;
        int lo = 0, hi = N_NODES;
        while (lo < hi) {
            int mid = (lo + hi) >> 1;
            if (batch[mid] < target) lo = mid + 1; else hi = mid;
        }
        bounds[tid] = lo;
    }
    __syncthreads();
    int lo = bounds[0], hi = bounds[1];
    int d = tid & 63, g = tid >> 6;
    float s = 0.f, m = -3.402823466e38f;
    for (int row = lo + g; row < hi; row += 4) {
        float v = __uint_as_float(((unsigned int)hb[(size_t)row * 64 + d]) << 16);
        v = fmaf(v, scale[d], shift[d]);
        s += v;
        m = fmaxf(m, v);
    }
    __shared__ float sh[8][64];
    sh[g][d] = s;
    sh[4 + g][d] = m;
    __syncthreads();
    if (tid < 64) {
        float S = sh[0][tid] + sh[1][tid] + sh[2][tid] + sh[3][tid];
        float M = fmaxf(fmaxf(sh[4][tid], sh[5][tid]), fmaxf(sh[6][tid], sh[7][tid]));
        int cnt = hi - lo;
        float mean = S / fmaxf((float)cnt, 1.0f);
        float mx = (cnt > 0) ? M : 0.0f;
        out[blockIdx.x * 64 + tid] = mean + mx;
    }
}

extern "C" void kernel_launch(void* const* d_in, const int* in_sizes, int n_in,
                              void* d_out, int out_size, void* d_ws, size_t ws_size,
                              hipStream_t stream) {
    const float* x     = (const float*)d_in[0];
    const int*   eidx  = (const int*)d_in[1];
    const int*   batch = (const int*)d_in[2];
    const float* W[3]  = {(const float*)d_in[3], (const float*)d_in[7],  (const float*)d_in[11]};
    const float* b[3]  = {(const float*)d_in[4], (const float*)d_in[8],  (const float*)d_in[12]};
    const float* gm[3] = {(const float*)d_in[5], (const float*)d_in[9],  (const float*)d_in[13]};
    const float* be[3] = {(const float*)d_in[6], (const float*)d_in[10], (const float*)d_in[14]};

    float*          hp    = (float*)d_ws;                               // N*64 f32
    unsigned short* tb    = (unsigned short*)(hp + (size_t)N_NODES * 64);   // N*64 bf16
    unsigned short* agg   = tb + (size_t)N_NODES * 64;                  // N*64 bf16
    unsigned short* rank  = agg + (size_t)N_NODES * 64;                 // E
    float* dinv     = (float*)(rank + N_EDGES);                         // N
    float* stats    = dinv + N_NODES;                                   // 3*128
    int*   cnt      = (int*)(stats + 384);                              // N
    int*   row_off  = cnt + N_NODES;                                    // N+1
    int*   blocksum = row_off + N_NODES + 1;                            // 128
    int*   csr_src  = blocksum + 128;                                   // E

    const int* srcp = eidx;
    const int* dstp = eidx + N_EDGES;

    hipMemsetAsync(stats, 0, (384 + N_NODES) * sizeof(float), stream);

    // CSR build (by destination) + dinv, atomic-free fill via rank
    hist_rank<<<(N_EDGES + 255) / 256, 256, 0, stream>>>(dstp, cnt, rank);
    scan_phase1<<<N_SCAN_BLOCKS, 256, 0, stream>>>(cnt, blocksum);
    scan_phase2<<<1, 128, 0, stream>>>(blocksum);
    scan_phase3<<<N_SCAN_BLOCKS, 256, 0, stream>>>(cnt, blocksum, row_off, dinv);
    fill_bucketed<<<FILL_CHUNKS * N_XCD, 256, 0, stream>>>(srcp, dstp, row_off, rank, csr_src);

    // layer 1
    gemm_f32<<<1024, 256, 0, stream>>>(x, W[0], dinv, tb);
    gather_agg<<<2048, 256, 0, stream>>>(csr_src, row_off, dinv, tb, b[0], agg, stats);

    // layer 2
    bnrelu<<<1024, 256, 0, stream>>>(agg, stats, gm[0], be[0], hp);
    gemm_f32<<<1024, 256, 0, stream>>>(hp, W[1], dinv, tb);
    gather_agg<<<2048, 256, 0, stream>>>(csr_src, row_off, dinv, tb, b[1], agg, stats + 128);

    // layer 3
    bnrelu<<<1024, 256, 0, stream>>>(agg, stats + 128, gm[1], be[1], hp);
    gemm_f32<<<1024, 256, 0, stream>>>(hp, W[2], dinv, tb);
    gather_agg<<<2048, 256, 0, stream>>>(csr_src, row_off, dinv, tb, b[2], agg, stats + 256);

    // pool with inline BN3
    pool_bn<<<N_GRAPHS, 256, 0, stream>>>(agg, batch, stats + 256, gm[2], be[2], (float*)d_out);
}